// Round 5
// baseline (304.923 us; speedup 1.0000x reference)
//
#include <hip/hip_runtime.h>
#include <cmath>
#include <complex>
#include <algorithm>

#define NB    256   // persistent blocks: 1 per CU, co-resident by construction
#define TB    1024
#define NTAIL 16    // blocks participating in tail phase-1
#define CAP_S 512   // max edges out of Co (out-degree ~Poisson(12))
#define CAP_T 64    // max distinct targets of Co's edges
#define CAP_M 4096  // max edges whose source is a target of Co (~12*12)
#define EB    64    // per-batch edges staged in LDS in tail phases

// ====================== host-side Wigner 3j (exact port, runs at .so load) =====================
namespace w3jhost {
static double fact(int n){
  static const double f[13]={1,1,2,6,24,120,720,5040,40320,362880,3628800,39916800,479001600};
  return f[n];
}
static double su2_cg(int j1,int m1,int j2,int m2,int j3,int m3){
  if(m3!=m1+m2) return 0.0;
  int vmin = std::max(std::max(-j1+j2+m3,-j1+m1),0);
  int vmax = std::min(std::min(j2+j3+m1, j3-j1+j2), j3+m3);
  double C = std::sqrt((double)(2*j3+1)*fact(j3+j1-j2)*fact(j3-j1+j2)*fact(j1+j2-j3)*fact(j3+m3)*fact(j3-m3)
            /(fact(j1+j2+j3+1)*fact(j1-m1)*fact(j1+m1)*fact(j2-m2)*fact(j2+m2)));
  double S=0.0;
  for(int v=vmin;v<=vmax;v++){
    double sgn = ((v+j2+m2)&1)?-1.0:1.0;
    S += sgn/fact(v)*fact(j2+j3+m1-v)*fact(j1-m1+v)/fact(j3-j1+j2-v)/fact(j3+m3-v)/fact(v+j1-j2-m3);
  }
  return C*S;
}
static void real_basis(int l, std::complex<double> q[7][7]){
  for(int i=0;i<7;i++)for(int j=0;j<7;j++) q[i][j]=0.0;
  const double r = std::sqrt(0.5);
  for(int m=-l;m<0;m++){ q[l+m][l-m]=r; q[l+m][l+m]=std::complex<double>(0.0,-r); }
  q[l][l]=1.0;
  for(int m=1;m<=l;m++){ double sg=(m&1)?-1.0:1.0; q[l+m][l+m]=sg*r; q[l+m][l-m]=std::complex<double>(0.0,sg*r); }
  std::complex<double> f;
  switch(l&3){ case 0: f={1,0};break; case 1: f={0,-1};break; case 2: f={-1,0};break; default: f={0,1};break; }
  for(int i=0;i<7;i++)for(int j=0;j<7;j++) q[i][j]*=f;
}
} // namespace w3jhost

struct W3JArg { float w[675]; };  // 7 paths concatenated, layout [i*(2l2+1)+j]*5+k

static W3JArg compute_w3j(){
  using namespace w3jhost;
  W3JArg out{};
  const int pl1[7]={0,1,1,2,2,3,3}, pl2[7]={2,1,3,0,2,1,3};
  int off=0;
  for(int p=0;p<7;p++){
    int l1=pl1[p], l2=pl2[p], l3=2;
    int n1=2*l1+1, n2=2*l2+1, n3=2*l3+1;
    double C[7][7][5];
    for(int i=0;i<7;i++)for(int k=0;k<7;k++)for(int n=0;n<5;n++) C[i][k][n]=0.0;
    for(int m1=-l1;m1<=l1;m1++)for(int m2=-l2;m2<=l2;m2++)
      if(std::abs(m1+m2)<=l3) C[l1+m1][l2+m2][l3+m1+m2]=su2_cg(l1,m1,l2,m2,l3,m1+m2);
    std::complex<double> Q1[7][7],Q2[7][7],Q3[7][7];
    real_basis(l1,Q1); real_basis(l2,Q2); real_basis(l3,Q3);
    double Cr[7][7][5]; double nrm=0.0;
    for(int a=0;a<n1;a++)for(int b=0;b<n2;b++)for(int c=0;c<n3;c++){
      std::complex<double> s(0.0,0.0);
      for(int i=0;i<n1;i++)for(int k=0;k<n2;k++)for(int n=0;n<n3;n++){
        double cv=C[i][k][n]; if(cv==0.0) continue;
        s += Q1[i][a]*Q2[k][b]*std::conj(Q3[n][c])*cv;  // einsum 'ij,kl,mn,ikn->jlm'
      }
      Cr[a][b][c]=s.real(); nrm+=s.real()*s.real();
    }
    nrm=std::sqrt(nrm);
    for(int a=0;a<n1;a++)for(int b=0;b<n2;b++)for(int c=0;c<n3;c++)
      out.w[off+(a*n2+b)*n3+c]=(float)(Cr[a][b][c]/nrm);
    off+=n1*n2*n3;
  }
  return out;
}
static const W3JArg g_w3j = compute_w3j();  // constant data; same every call

// ====================== device helpers ======================
__device__ __forceinline__ void calc_sh(float x,float y,float z,float* sh){
  float x2=x*x,y2=y*y,z2=z*z;
  const float s3=1.7320508075688772f, s5=2.2360679774997896f, s15=3.872983346207417f;
  const float s70_4=2.091650066335189f, s105=10.246950765959598f, s42_4=1.6201851746019651f;
  const float s7_2=1.3228756555322954f, s105_2=5.123475382979799f;
  sh[0]=1.f;
  sh[1]=s3*x; sh[2]=s3*y; sh[3]=s3*z;
  sh[4]=s15*x*z; sh[5]=s15*x*y; sh[6]=s5*(y2-0.5f*(x2+z2)); sh[7]=s15*y*z; sh[8]=0.5f*s15*(z2-x2);
  sh[9]=s70_4*x*(3.f*z2-x2); sh[10]=s105*x*y*z; sh[11]=s42_4*x*(5.f*y2-1.f);
  sh[12]=s7_2*y*(5.f*y2-3.f); sh[13]=s42_4*z*(5.f*y2-1.f); sh[14]=s105_2*y*(z2-x2); sh[15]=s70_4*z*(z2-3.f*x2);
}

// device-scope grid barrier; each bars[i] used exactly once per launch.
// Poll backoff: round-4's s_sleep(1) (~27ns polls x 255 CUs) flooded the coherent
// point that the real atomics also need. s_sleep(32) ~0.85us polls after warmup.
__device__ __forceinline__ void gridbar(int* ctr){
  __syncthreads();
  if(threadIdx.x==0){
    __threadfence();   // release
    __hip_atomic_fetch_add(ctr,1,__ATOMIC_ACQ_REL,__HIP_MEMORY_SCOPE_AGENT);
    int it=0;
    while(__hip_atomic_load(ctr,__ATOMIC_ACQUIRE,__HIP_MEMORY_SCOPE_AGENT)<NB){
      if(it<8) __builtin_amdgcn_s_sleep(2);
      else     __builtin_amdgcn_s_sleep(32);
      ++it;
    }
    __threadfence();   // acquire
  }
  __syncthreads();
}

// ====================== the persistent mega-kernel ======================
__global__ void __launch_bounds__(TB,1)
k_mega(const float* __restrict__ x, const float* __restrict__ pos,
       const int* __restrict__ efrom, const int* __restrict__ eto,
       const float* __restrict__ W1, const float* __restrict__ W2,
       const float* __restrict__ tp2, int N, int E,
       int* __restrict__ counts, int* __restrict__ flagslot,
       unsigned long long* __restrict__ packed,
       int* __restrict__ numS, int* __restrict__ numT, int* __restrict__ numM,
       int* __restrict__ S, int* __restrict__ M, float* __restrict__ nmid_g,
       int* __restrict__ bars, W3JArg w3, float* __restrict__ out5){
  __shared__ float W1s[600];
  __shared__ float W2s[600];
  __shared__ float w3s[675];
  __shared__ float tp2s[35];
  __shared__ float shs[EB*16];
  __shared__ float embs[EB*20];
  __shared__ float hs[EB*30];
  __shared__ float tws[EB*20];
  __shared__ float es_[EB];
  __shared__ float dd_[EB];
  __shared__ int   sl_[EB];
  __shared__ float acc[5];
  __shared__ unsigned long long bmax;

  const int tid=threadIdx.x;
  const int gtid=blockIdx.x*TB+tid;
  const int gstride=NB*TB;

  // ---- phase Z: zero the bulk workspace in-kernel ----
  for(int i=gtid;i<N;i+=gstride){ counts[i]=0; flagslot[i]=0; }
  for(int i=gtid;i<CAP_T*80;i+=gstride) nmid_g[i]=0.f;
  if(tid==0) bmax=0ull;
  gridbar(&bars[0]);

  // ---- phase A: bincount, FIRE-AND-FORGET atomics (round-4's return-atomics
  //      produced 600k x 32B coherent-point write-throughs = the 19.2MB WRITE_SIZE) ----
  {
    int nQ=(E+3)>>2;
    for(int q=gtid;q<nQ;q+=gstride){
      int e=q*4;
      if(e+3<E){
        int4 v=*reinterpret_cast<const int4*>(eto+e);
        atomicAdd(&counts[v.x],1); atomicAdd(&counts[v.y],1);
        atomicAdd(&counts[v.z],1); atomicAdd(&counts[v.w],1);
      } else {
        for(;e<E;e++) atomicAdd(&counts[eto[e]],1);
      }
    }
  }
  gridbar(&bars[1]);

  // ---- phase A2: grid-strided argmax over counts ----
  {
    unsigned long long lm=0ull;
    for(int i=gtid;i<N;i+=gstride){
      int c=counts[i];
      if(c>0){
        unsigned long long d=(((unsigned long long)(unsigned)c)<<32)
                            |(unsigned long long)(0xFFFFFFFFu-(unsigned)i);
        lm=max(lm,d);
      }
    }
    #pragma unroll
    for(int off=32;off;off>>=1){
      unsigned long long o=__shfl_xor(lm,off);
      lm=max(lm,o);
    }
    if((tid&63)==0) atomicMax(&bmax,lm);
    __syncthreads();
    if(tid==0) atomicMax(packed,bmax);
  }
  gridbar(&bars[2]);

  // ---- phase B: collect edges out of Co + CAS-dedup'd target slot allocation ----
  {
    unsigned long long pk=__hip_atomic_load(packed,__ATOMIC_RELAXED,__HIP_MEMORY_SCOPE_AGENT);
    int co=(int)(0xFFFFFFFFu-(unsigned)(pk&0xFFFFFFFFull));   // numpy argmax (first max)
    int nQ=(E+3)>>2;
    for(int q=gtid;q<nQ;q+=gstride){
      int e=q*4;
      if(e+3<E){
        int4 v=*reinterpret_cast<const int4*>(efrom+e);
        int f[4]={v.x,v.y,v.z,v.w};
        #pragma unroll
        for(int k=0;k<4;k++){
          if(f[k]==co){
            int p=atomicAdd(numS,1);
            if(p<CAP_S) S[p]=e+k;
            int t=eto[e+k];
            int old=atomicCAS(&flagslot[t],0,-1);
            if(old==0){
              int s=atomicAdd(numT,1);
              __hip_atomic_store(&flagslot[t],(s<CAP_T)?(s+2):0,__ATOMIC_RELAXED,__HIP_MEMORY_SCOPE_AGENT);
            }
          }
        }
      } else {
        for(;e<E;e++){
          if(efrom[e]==co){
            int p=atomicAdd(numS,1);
            if(p<CAP_S) S[p]=e;
            int t=eto[e];
            int old=atomicCAS(&flagslot[t],0,-1);
            if(old==0){
              int s=atomicAdd(numT,1);
              __hip_atomic_store(&flagslot[t],(s<CAP_T)?(s+2):0,__ATOMIC_RELAXED,__HIP_MEMORY_SCOPE_AGENT);
            }
          }
        }
      }
    }
  }
  gridbar(&bars[3]);

  // ---- phase C: scan for edges whose source is a flagged target -> compact list M ----
  {
    int nQ=(E+3)>>2;
    for(int q=gtid;q<nQ;q+=gstride){
      int e=q*4;
      if(e+3<E){
        int4 v=*reinterpret_cast<const int4*>(efrom+e);
        int f0=flagslot[v.x], f1=flagslot[v.y], f2=flagslot[v.z], f3=flagslot[v.w];
        if(f0>=2){int p=atomicAdd(numM,1); if(p<CAP_M) M[p]=e;  }
        if(f1>=2){int p=atomicAdd(numM,1); if(p<CAP_M) M[p]=e+1;}
        if(f2>=2){int p=atomicAdd(numM,1); if(p<CAP_M) M[p]=e+2;}
        if(f3>=2){int p=atomicAdd(numM,1); if(p<CAP_M) M[p]=e+3;}
      } else {
        for(;e<E;e++)
          if(flagslot[efrom[e]]>=2){int p=atomicAdd(numM,1); if(p<CAP_M) M[p]=e;}
      }
    }
  }
  gridbar(&bars[4]);

  // ---- phase D: tail phase-1 (radial MLP + sh -> nmid), spread over NTAIL blocks ----
  {
    int nm=__hip_atomic_load(numM,__ATOMIC_RELAXED,__HIP_MEMORY_SCOPE_AGENT);
    if(nm>CAP_M) nm=CAP_M;
    if(blockIdx.x<NTAIL){
      for(int i=tid;i<600;i+=TB){ W1s[i]=W1[i]; W2s[i]=W2[i]; }
      int per=(nm+NTAIL-1)/NTAIL;
      int lo=min(nm,(int)blockIdx.x*per), hi=min(nm,lo+per);
      for(int base=lo;base<hi;base+=EB){
        int cnt=min(EB,hi-base);
        __syncthreads();   // W1s ready (1st iter) + LDS reuse across batches
        // A0: per-edge meta + spherical harmonics
        if(tid<cnt){
          int e=M[base+tid];
          int a=efrom[e];
          int fs=flagslot[a];
          if(fs<2){ sl_[tid]=-1; }
          else{
            int b=eto[e];
            float dx=pos[3*b]-pos[3*a], dy=pos[3*b+1]-pos[3*a+1], dz=pos[3*b+2]-pos[3*a+2];
            float d=sqrtf(dx*dx+dy*dy+dz*dz);
            float inv=1.f/d;
            calc_sh(dx*inv,dy*inv,dz*inv,&shs[tid*16]);
            dd_[tid]=d;
            es_[tid]=x[b]*(0.18257418583505536f*0.4082482904638631f); // 1/sqrt30 * 1/sqrt6
            sl_[tid]=fs-2;
          }
        }
        __syncthreads();
        // A1: radial embedding, one (edge,i) per task
        for(int t=tid;t<cnt*20;t+=TB){
          int ee=t/20, i=t-ee*20;
          if(sl_[ee]>=0){
            const float inv_step=21.f/3.5f;
            const float pref=(float)(1.14136*7.3890560989306495);  // 1.14136*e^2
            float di=dd_[ee]*inv_step;
            float A=di-(float)i, B=(float)(i+2)-di;
            float ua=(A>0.f)?expf(-1.f/A):0.f;
            float ub=(B>0.f)?expf(-1.f/B):0.f;
            embs[ee*20+i]=pref*ua*ub;
          }
        }
        __syncthreads();
        // B: MLP layer 1, one (edge,j) per task
        for(int t=tid;t<cnt*30;t+=TB){
          int ee=t/30, j=t-ee*30;
          if(sl_[ee]>=0){
            float z=0.f;
            #pragma unroll
            for(int i=0;i<20;i++) z+=embs[ee*20+i]*W1s[i*30+j];
            z*=0.22360679774997896f;                  // 1/sqrt20
            hs[ee*30+j]=1.679177f*z/(1.f+expf(-z));   // NORM2MOM * silu
          }
        }
        __syncthreads();
        // C: MLP layer 2, one (edge,c) per task
        for(int t=tid;t<cnt*20;t+=TB){
          int ee=t/20, c=t-ee*20;
          if(sl_[ee]>=0){
            float v=0.f;
            #pragma unroll
            for(int j=0;j<30;j++) v+=hs[ee*30+j]*W2s[j*20+c];
            tws[ee*20+c]=v;
          }
        }
        __syncthreads();
        // D: mid accumulation into GLOBAL nmid (device-scope atomics)
        for(int t=tid;t<cnt*80;t+=TB){
          int ee=t/80, oo=t-ee*80;
          int sl=sl_[ee];
          if(sl>=0){
            int l,u,mm;
            if(oo<5){ l=0; u=oo; mm=0; }
            else if(oo<20){ int r=oo-5;  l=1; u=r/3; mm=r-u*3; }
            else if(oo<45){ int r=oo-20; l=2; u=r/5; mm=r-u*5; }
            else          { int r=oo-45; l=3; u=r/7; mm=r-u*7; }
            float val=es_[ee]*tws[ee*20+l*5+u]*shs[ee*16+l*l+mm];
            atomicAdd(&nmid_g[sl*80+oo],val);
          }
        }
      }
    }
  }
  gridbar(&bars[5]);
  if(blockIdx.x!=0) return;

  // ---- phase E: second tensor product over edges out of Co (block 0 only) ----
  for(int i=tid;i<675;i+=TB) w3s[i]=w3.w[i];
  if(tid<35) tp2s[tid]=tp2[tid];
  if(tid<5) acc[tid]=0.f;
  int ns=__hip_atomic_load(numS,__ATOMIC_RELAXED,__HIP_MEMORY_SCOPE_AGENT);
  if(ns>CAP_S) ns=CAP_S;
  for(int base=0;base<ns;base+=EB){
    int cnt=min(EB,ns-base);
    __syncthreads();
    if(tid<cnt){
      int e=S[base+tid];
      int a=efrom[e], b=eto[e];
      int fs=flagslot[b];
      if(fs<2){ sl_[tid]=-1; }
      else{
        float dx=pos[3*b]-pos[3*a], dy=pos[3*b+1]-pos[3*a+1], dz=pos[3*b+2]-pos[3*a+2];
        float d=sqrtf(dx*dx+dy*dy+dz*dz);
        float inv=1.f/d;
        calc_sh(dx*inv,dy*inv,dz*inv,&shs[tid*16]);
        sl_[tid]=fs-2;
      }
    }
    __syncthreads();
    for(int t=tid;t<cnt*35;t+=TB){
      int ee=t/35, r=t-ee*35, p=r/5, u=r-p*5;
      int sl=sl_[ee];
      if(sl>=0){
        int l1=(p+1)>>1;                         // 0,1,1,2,2,3,3
        int l2=(0x3636>>(2*p))&3;                // 2,1,3,0,2,1,3
        const unsigned long long wbpack=
          (25ULL<<9)|(70ULL<<18)|(175ULL<<27)|(200ULL<<36)|(325ULL<<45)|(430ULL<<54);
        int wb=(int)((wbpack>>(9*p))&511ULL);    // 0,25,70,175,200,325,430
        int n1=2*l1+1, n2=2*l2+1;
        float tu=tp2s[p*5+u];
        float o0=0.f,o1=0.f,o2=0.f,o3=0.f,o4=0.f;
        const float* mrow=&nmid_g[sl*80+5*l1*l1+u*n1];
        const float* shrow=&shs[ee*16+l2*l2];
        const float* Wp=&w3s[wb];
        for(int i=0;i<n1;i++){
          float mi=mrow[i]*tu;
          for(int j=0;j<n2;j++){
            float c=mi*shrow[j];
            const float* Wk=Wp+(i*n2+j)*5;
            o0+=Wk[0]*c; o1+=Wk[1]*c; o2+=Wk[2]*c; o3+=Wk[3]*c; o4+=Wk[4]*c;
          }
        }
        atomicAdd(&acc[0],o0); atomicAdd(&acc[1],o1); atomicAdd(&acc[2],o2);
        atomicAdd(&acc[3],o3); atomicAdd(&acc[4],o4);
      }
    }
    __syncthreads();
  }
  __syncthreads();
  const float scale=0.37796447300922725f*0.4082482904638631f;  // ALPHA2 * 1/sqrt(6)
  if(tid<5) out5[tid]=acc[tid]*scale;
}

// ====================== launch ======================
extern "C" void kernel_launch(void* const* d_in, const int* in_sizes, int n_in,
                              void* d_out, int out_size, void* d_ws, size_t ws_size,
                              hipStream_t stream){
  const float* x    =(const float*)d_in[0];
  const float* pos  =(const float*)d_in[1];
  const int*   efrom=(const int*)  d_in[2];
  const int*   eto  =(const int*)  d_in[3];
  const float* W1   =(const float*)d_in[4];
  const float* W2   =(const float*)d_in[5];
  const float* tp2  =(const float*)d_in[6];
  int N=in_sizes[0], E=in_sizes[2];

  char* ws=(char*)d_ws;
  size_t o=0;
  unsigned long long* packed=(unsigned long long*)(ws+o); o+=8;
  int* numS=(int*)(ws+o);                   o+=4;
  int* numT=(int*)(ws+o);                   o+=4;
  int* numM=(int*)(ws+o);                   o+=4;
  int* bars=(int*)(ws+o);                   o+=8*4;
  size_t ctrl=o;                            // only this prefix needs host-side zeroing
  o=(o+63)&~(size_t)63;
  int* counts=(int*)(ws+o);                 o+=(size_t)N*4;
  int* flagslot=(int*)(ws+o);               o+=(size_t)N*4;
  int* S=(int*)(ws+o);                      o+=(size_t)CAP_S*4;
  int* M=(int*)(ws+o);                      o+=(size_t)CAP_M*4;
  float* nmid_g=(float*)(ws+o);             o+=(size_t)CAP_T*80*4;

  hipMemsetAsync(d_ws,0,ctrl,stream);       // 52 B: barrier counters + control words

  k_mega<<<NB,TB,0,stream>>>(x,pos,efrom,eto,W1,W2,tp2,N,E,
                             counts,flagslot,packed,numS,numT,numM,
                             S,M,nmid_g,bars,g_w3j,(float*)d_out);
}

// Round 7
// 166.706 us; speedup vs baseline: 1.8291x; 1.8291x over previous
//
#include <hip/hip_runtime.h>
#include <cmath>
#include <complex>
#include <algorithm>

#define NB    256   // persistent blocks: 1 per CU, co-resident by construction
#define TB    1024
#define NTAIL 16    // blocks participating in tail phase-1
#define CAP_S 512   // max edges out of Co (out-degree ~Poisson(12))
#define CAP_T 64    // max distinct targets of Co's edges
#define CAP_M 4096  // max edges whose source is a target of Co (~12*12)
#define EB    64    // per-batch edges staged in LDS in tail phases

// ====================== host-side Wigner 3j (exact port, runs at .so load) =====================
namespace w3jhost {
static double fact(int n){
  static const double f[13]={1,1,2,6,24,120,720,5040,40320,362880,3628800,39916800,479001600};
  return f[n];
}
static double su2_cg(int j1,int m1,int j2,int m2,int j3,int m3){
  if(m3!=m1+m2) return 0.0;
  int vmin = std::max(std::max(-j1+j2+m3,-j1+m1),0);
  int vmax = std::min(std::min(j2+j3+m1, j3-j1+j2), j3+m3);
  double C = std::sqrt((double)(2*j3+1)*fact(j3+j1-j2)*fact(j3-j1+j2)*fact(j1+j2-j3)*fact(j3+m3)*fact(j3-m3)
            /(fact(j1+j2+j3+1)*fact(j1-m1)*fact(j1+m1)*fact(j2-m2)*fact(j2+m2)));
  double S=0.0;
  for(int v=vmin;v<=vmax;v++){
    double sgn = ((v+j2+m2)&1)?-1.0:1.0;
    S += sgn/fact(v)*fact(j2+j3+m1-v)*fact(j1-m1+v)/fact(j3-j1+j2-v)/fact(j3+m3-v)/fact(v+j1-j2-m3);
  }
  return C*S;
}
static void real_basis(int l, std::complex<double> q[7][7]){
  for(int i=0;i<7;i++)for(int j=0;j<7;j++) q[i][j]=0.0;
  const double r = std::sqrt(0.5);
  for(int m=-l;m<0;m++){ q[l+m][l-m]=r; q[l+m][l+m]=std::complex<double>(0.0,-r); }
  q[l][l]=1.0;
  for(int m=1;m<=l;m++){ double sg=(m&1)?-1.0:1.0; q[l+m][l+m]=sg*r; q[l+m][l-m]=std::complex<double>(0.0,sg*r); }
  std::complex<double> f;
  switch(l&3){ case 0: f={1,0};break; case 1: f={0,-1};break; case 2: f={-1,0};break; default: f={0,1};break; }
  for(int i=0;i<7;i++)for(int j=0;j<7;j++) q[i][j]*=f;
}
} // namespace w3jhost

struct W3JArg { float w[675]; };  // 7 paths concatenated, layout [i*(2l2+1)+j]*5+k

static W3JArg compute_w3j(){
  using namespace w3jhost;
  W3JArg out{};
  const int pl1[7]={0,1,1,2,2,3,3}, pl2[7]={2,1,3,0,2,1,3};
  int off=0;
  for(int p=0;p<7;p++){
    int l1=pl1[p], l2=pl2[p], l3=2;
    int n1=2*l1+1, n2=2*l2+1, n3=2*l3+1;
    double C[7][7][5];
    for(int i=0;i<7;i++)for(int k=0;k<7;k++)for(int n=0;n<5;n++) C[i][k][n]=0.0;
    for(int m1=-l1;m1<=l1;m1++)for(int m2=-l2;m2<=l2;m2++)
      if(std::abs(m1+m2)<=l3) C[l1+m1][l2+m2][l3+m1+m2]=su2_cg(l1,m1,l2,m2,l3,m1+m2);
    std::complex<double> Q1[7][7],Q2[7][7],Q3[7][7];
    real_basis(l1,Q1); real_basis(l2,Q2); real_basis(l3,Q3);
    double Cr[7][7][5]; double nrm=0.0;
    for(int a=0;a<n1;a++)for(int b=0;b<n2;b++)for(int c=0;c<n3;c++){
      std::complex<double> s(0.0,0.0);
      for(int i=0;i<n1;i++)for(int k=0;k<n2;k++)for(int n=0;n<n3;n++){
        double cv=C[i][k][n]; if(cv==0.0) continue;
        s += Q1[i][a]*Q2[k][b]*std::conj(Q3[n][c])*cv;  // einsum 'ij,kl,mn,ikn->jlm'
      }
      Cr[a][b][c]=s.real(); nrm+=s.real()*s.real();
    }
    nrm=std::sqrt(nrm);
    for(int a=0;a<n1;a++)for(int b=0;b<n2;b++)for(int c=0;c<n3;c++)
      out.w[off+(a*n2+b)*n3+c]=(float)(Cr[a][b][c]/nrm);
    off+=n1*n2*n3;
  }
  return out;
}
static const W3JArg g_w3j = compute_w3j();  // constant data; same every call

// ====================== device helpers ======================
__device__ __forceinline__ void calc_sh(float x,float y,float z,float* sh){
  float x2=x*x,y2=y*y,z2=z*z;
  const float s3=1.7320508075688772f, s5=2.2360679774997896f, s15=3.872983346207417f;
  const float s70_4=2.091650066335189f, s105=10.246950765959598f, s42_4=1.6201851746019651f;
  const float s7_2=1.3228756555322954f, s105_2=5.123475382979799f;
  sh[0]=1.f;
  sh[1]=s3*x; sh[2]=s3*y; sh[3]=s3*z;
  sh[4]=s15*x*z; sh[5]=s15*x*y; sh[6]=s5*(y2-0.5f*(x2+z2)); sh[7]=s15*y*z; sh[8]=0.5f*s15*(z2-x2);
  sh[9]=s70_4*x*(3.f*z2-x2); sh[10]=s105*x*y*z; sh[11]=s42_4*x*(5.f*y2-1.f);
  sh[12]=s7_2*y*(5.f*y2-3.f); sh[13]=s42_4*z*(5.f*y2-1.f); sh[14]=s105_2*y*(z2-x2); sh[15]=s70_4*z*(z2-3.f*x2);
}

// explicitly-coherent (device/agent-level) scalar accesses: bypass the non-coherent
// per-XCD caches so NO L2 writeback/invalidate fences are needed anywhere.
__device__ __forceinline__ void cstore(int* p,int v){ __hip_atomic_store(p,v,__ATOMIC_RELAXED,__HIP_MEMORY_SCOPE_AGENT); }
__device__ __forceinline__ int  cload(const int* p){ return __hip_atomic_load(p,__ATOMIC_RELAXED,__HIP_MEMORY_SCOPE_AGENT); }
__device__ __forceinline__ void cstoref(float* p,float v){ __hip_atomic_store(p,v,__ATOMIC_RELAXED,__HIP_MEMORY_SCOPE_AGENT); }
__device__ __forceinline__ float cloadf(const float* p){ return __hip_atomic_load(p,__ATOMIC_RELAXED,__HIP_MEMORY_SCOPE_AGENT); }

// FENCE-FREE grid barrier. Rounds 4/5 measured ~150us of unexplained cost with
// __threadfence() barriers (agent release/acquire => buffer_wbl2/buffer_inv = full
// per-XCD L2 tag walks). All cross-block data is explicitly coherent, so the barrier
// only needs: drain my outstanding memory ops, then count arrivals.
__device__ __forceinline__ void gridbar(int* ctr){
  __syncthreads();
  if(threadIdx.x==0){
    asm volatile("s_waitcnt vmcnt(0) lgkmcnt(0)" ::: "memory");
    __hip_atomic_fetch_add(ctr,1,__ATOMIC_RELAXED,__HIP_MEMORY_SCOPE_AGENT);
    int it=0;
    while(__hip_atomic_load(ctr,__ATOMIC_RELAXED,__HIP_MEMORY_SCOPE_AGENT)<NB){
      if(it<16) __builtin_amdgcn_s_sleep(2);
      else      __builtin_amdgcn_s_sleep(16);
      ++it;
    }
  }
  __syncthreads();
}

// ====================== the persistent mega-kernel ======================
__global__ void __launch_bounds__(TB,1)
k_mega(const float* __restrict__ x, const float* __restrict__ pos,
       const int* __restrict__ efrom, const int* __restrict__ eto,
       const float* __restrict__ W1, const float* __restrict__ W2,
       const float* __restrict__ tp2, int N, int E,
       int* __restrict__ counts,
       unsigned long long* __restrict__ packed,
       int* __restrict__ numS, int* __restrict__ numM,
       int* __restrict__ S, int* __restrict__ M, float* __restrict__ nmid_g,
       int* __restrict__ bars, W3JArg w3, float* __restrict__ out5){
  __shared__ float W1s[600];
  __shared__ float W2s[600];
  __shared__ float w3s[675];
  __shared__ float tp2s[35];
  __shared__ float shs[EB*16];
  __shared__ float embs[EB*20];
  __shared__ float hs[EB*30];
  __shared__ float tws[EB*20];
  __shared__ float es_[EB];
  __shared__ float dd_[EB];
  __shared__ int   sl_[EB];
  __shared__ int   Tlist[CAP_T];
  __shared__ int   Te[CAP_T];
  __shared__ float acc[5];
  __shared__ unsigned long long bmax;
  __shared__ int   nTs;

  const int tid=threadIdx.x;
  const int gtid=blockIdx.x*TB+tid;
  const int gstride=NB*TB;

  // ---- phase Z: coherent-zero counts + nmid (write-through; no fence needed) ----
  for(int i=gtid;i<N;i+=gstride) cstore(&counts[i],0);
  for(int i=gtid;i<CAP_T*80;i+=gstride) cstoref(&nmid_g[i],0.f);
  if(tid==0) bmax=0ull;
  gridbar(&bars[0]);

  // ---- phase A: bincount + FUSED argmax via atomicAdd-return candidates
  //      (r4/r5 A/B proved return-atomics cost nothing; fusing kills a pass+barrier) ----
  {
    unsigned long long lm=0ull;
    int nQ=(E+3)>>2;
    for(int q=gtid;q<nQ;q+=gstride){
      int e=q*4;
      if(e+3<E){
        int4 v=*reinterpret_cast<const int4*>(eto+e);
        int c0=atomicAdd(&counts[v.x],1)+1;
        int c1=atomicAdd(&counts[v.y],1)+1;
        int c2=atomicAdd(&counts[v.z],1)+1;
        int c3=atomicAdd(&counts[v.w],1)+1;
        unsigned long long d0=(((unsigned long long)(unsigned)c0)<<32)|(unsigned long long)(0xFFFFFFFFu-(unsigned)v.x);
        unsigned long long d1=(((unsigned long long)(unsigned)c1)<<32)|(unsigned long long)(0xFFFFFFFFu-(unsigned)v.y);
        unsigned long long d2=(((unsigned long long)(unsigned)c2)<<32)|(unsigned long long)(0xFFFFFFFFu-(unsigned)v.z);
        unsigned long long d3=(((unsigned long long)(unsigned)c3)<<32)|(unsigned long long)(0xFFFFFFFFu-(unsigned)v.w);
        lm=max(max(max(max(lm,d0),d1),d2),d3);
      } else {
        for(;e<E;e++){
          int t=eto[e];
          int c=atomicAdd(&counts[t],1)+1;
          unsigned long long dd=(((unsigned long long)(unsigned)c)<<32)|(unsigned long long)(0xFFFFFFFFu-(unsigned)t);
          lm=max(lm,dd);
        }
      }
    }
    #pragma unroll
    for(int off=32;off;off>>=1){
      unsigned long long o=__shfl_xor(lm,off);
      lm=max(lm,o);
    }
    if((tid&63)==0) atomicMax(&bmax,lm);
    __syncthreads();
    if(tid==0) atomicMax(packed,bmax);
  }
  gridbar(&bars[1]);

  // ---- phase B: collect edges out of Co (coherent appends; NO flagslot array) ----
  {
    unsigned long long pk=__hip_atomic_load(packed,__ATOMIC_RELAXED,__HIP_MEMORY_SCOPE_AGENT);
    int co=(int)(0xFFFFFFFFu-(unsigned)(pk&0xFFFFFFFFull));   // numpy argmax (first max)
    int nQ=(E+3)>>2;
    for(int q=gtid;q<nQ;q+=gstride){
      int e=q*4;
      if(e+3<E){
        int4 v=*reinterpret_cast<const int4*>(efrom+e);
        int f[4]={v.x,v.y,v.z,v.w};
        #pragma unroll
        for(int k=0;k<4;k++){
          if(f[k]==co){
            int p=atomicAdd(numS,1);
            if(p<CAP_S) cstore(&S[p],e+k);
          }
        }
      } else {
        for(;e<E;e++){
          if(efrom[e]==co){
            int p=atomicAdd(numS,1);
            if(p<CAP_S) cstore(&S[p],e);
          }
        }
      }
    }
  }
  gridbar(&bars[2]);

  // ---- phase C: every block rebuilds the tiny target list (deterministic dedup),
  //      then scans efrom for edges whose source is in it -> compact list M ----
  {
    int ns=cload(numS); if(ns>CAP_S) ns=CAP_S;
    int nsc=min(ns,CAP_T);   // dedup window: first CAP_T S-entries (>= all realistic cases)
    if(tid<nsc) Te[tid]=eto[cload(&S[tid])];
    __syncthreads();
    if(tid<64){              // wave 0: ballot-based dedup + prefix slots
      bool keep=false; int myv=0;
      if(tid<nsc){
        myv=Te[tid];
        keep=true;
        for(int k=0;k<tid;k++) if(Te[k]==myv){ keep=false; break; }
      }
      unsigned long long mask=__ballot(keep);
      if(keep){
        int slot=__popcll(mask&((1ull<<tid)-1ull));
        Tlist[slot]=myv;
      }
      if(tid==0) nTs=__popcll(mask);
    }
    __syncthreads();
    int nT=nTs;
    int nQ=(E+3)>>2;
    for(int q=gtid;q<nQ;q+=gstride){
      int e=q*4;
      if(e+3<E){
        int4 v=*reinterpret_cast<const int4*>(efrom+e);
        int hit0=0,hit1=0,hit2=0,hit3=0;
        for(int k=0;k<nT;k++){           // LDS broadcast reads: conflict-free
          int t=Tlist[k];
          hit0|=(v.x==t); hit1|=(v.y==t); hit2|=(v.z==t); hit3|=(v.w==t);
        }
        if(hit0){int p=atomicAdd(numM,1); if(p<CAP_M) cstore(&M[p],e);  }
        if(hit1){int p=atomicAdd(numM,1); if(p<CAP_M) cstore(&M[p],e+1);}
        if(hit2){int p=atomicAdd(numM,1); if(p<CAP_M) cstore(&M[p],e+2);}
        if(hit3){int p=atomicAdd(numM,1); if(p<CAP_M) cstore(&M[p],e+3);}
      } else {
        for(;e<E;e++){
          int s=efrom[e]; int hit=0;
          for(int k=0;k<nT;k++) hit|=(s==Tlist[k]);
          if(hit){int p=atomicAdd(numM,1); if(p<CAP_M) cstore(&M[p],e);}
        }
      }
    }
  }
  gridbar(&bars[3]);

  // ---- phase D: tail phase-1 (radial MLP + sh -> nmid), spread over NTAIL blocks ----
  {
    int nm=cload(numM); if(nm>CAP_M) nm=CAP_M;
    int nT=nTs;
    if(blockIdx.x<NTAIL){
      for(int i=tid;i<600;i+=TB){ W1s[i]=W1[i]; W2s[i]=W2[i]; }   // read-only: cached
      int per=(nm+NTAIL-1)/NTAIL;
      int lo=min(nm,(int)blockIdx.x*per), hi=min(nm,lo+per);
      for(int base=lo;base<hi;base+=EB){
        int cnt=min(EB,hi-base);
        __syncthreads();   // W1s ready (1st iter) + LDS reuse across batches
        // A0: per-edge meta + spherical harmonics (slot via Tlist search)
        if(tid<cnt){
          int e=cload(&M[base+tid]);
          int a=efrom[e];
          int sl=-1;
          for(int k=0;k<nT;k++) if(Tlist[k]==a){ sl=k; break; }
          sl_[tid]=sl;
          if(sl>=0){
            int b=eto[e];
            float dx=pos[3*b]-pos[3*a], dy=pos[3*b+1]-pos[3*a+1], dz=pos[3*b+2]-pos[3*a+2];
            float d=sqrtf(dx*dx+dy*dy+dz*dz);
            float inv=1.f/d;
            calc_sh(dx*inv,dy*inv,dz*inv,&shs[tid*16]);
            dd_[tid]=d;
            es_[tid]=x[b]*(0.18257418583505536f*0.4082482904638631f); // 1/sqrt30 * 1/sqrt6
          }
        }
        __syncthreads();
        // A1: radial embedding, one (edge,i) per task
        for(int t=tid;t<cnt*20;t+=TB){
          int ee=t/20, i=t-ee*20;
          if(sl_[ee]>=0){
            const float inv_step=21.f/3.5f;
            const float pref=(float)(1.14136*7.3890560989306495);  // 1.14136*e^2
            float di=dd_[ee]*inv_step;
            float A=di-(float)i, B=(float)(i+2)-di;
            float ua=(A>0.f)?expf(-1.f/A):0.f;
            float ub=(B>0.f)?expf(-1.f/B):0.f;
            embs[ee*20+i]=pref*ua*ub;
          }
        }
        __syncthreads();
        // B: MLP layer 1, one (edge,j) per task
        for(int t=tid;t<cnt*30;t+=TB){
          int ee=t/30, j=t-ee*30;
          if(sl_[ee]>=0){
            float z=0.f;
            #pragma unroll
            for(int i=0;i<20;i++) z+=embs[ee*20+i]*W1s[i*30+j];
            z*=0.22360679774997896f;                  // 1/sqrt20
            hs[ee*30+j]=1.679177f*z/(1.f+expf(-z));   // NORM2MOM * silu
          }
        }
        __syncthreads();
        // C: MLP layer 2, one (edge,c) per task
        for(int t=tid;t<cnt*20;t+=TB){
          int ee=t/20, c=t-ee*20;
          if(sl_[ee]>=0){
            float v=0.f;
            #pragma unroll
            for(int j=0;j<30;j++) v+=hs[ee*30+j]*W2s[j*20+c];
            tws[ee*20+c]=v;
          }
        }
        __syncthreads();
        // D: mid accumulation into GLOBAL nmid (device-scope atomics = coherent)
        for(int t=tid;t<cnt*80;t+=TB){
          int ee=t/80, oo=t-ee*80;
          int sl=sl_[ee];
          if(sl>=0){
            int l,u,mm;
            if(oo<5){ l=0; u=oo; mm=0; }
            else if(oo<20){ int r=oo-5;  l=1; u=r/3; mm=r-u*3; }
            else if(oo<45){ int r=oo-20; l=2; u=r/5; mm=r-u*5; }
            else          { int r=oo-45; l=3; u=r/7; mm=r-u*7; }
            float val=es_[ee]*tws[ee*20+l*5+u]*shs[ee*16+l*l+mm];
            atomicAdd(&nmid_g[sl*80+oo],val);
          }
        }
      }
    }
  }
  gridbar(&bars[4]);
  if(blockIdx.x!=0) return;

  // ---- phase E: second tensor product over edges out of Co (block 0 only) ----
  for(int i=tid;i<675;i+=TB) w3s[i]=w3.w[i];
  if(tid<35) tp2s[tid]=tp2[tid];
  if(tid<5) acc[tid]=0.f;
  int ns=cload(numS); if(ns>CAP_S) ns=CAP_S;
  int nT=nTs;
  for(int base=0;base<ns;base+=EB){
    int cnt=min(EB,ns-base);
    __syncthreads();
    if(tid<cnt){
      int e=cload(&S[base+tid]);
      int a=efrom[e], b=eto[e];
      int sl=-1;
      for(int k=0;k<nT;k++) if(Tlist[k]==b){ sl=k; break; }
      sl_[tid]=sl;
      if(sl>=0){
        float dx=pos[3*b]-pos[3*a], dy=pos[3*b+1]-pos[3*a+1], dz=pos[3*b+2]-pos[3*a+2];
        float d=sqrtf(dx*dx+dy*dy+dz*dz);
        float inv=1.f/d;
        calc_sh(dx*inv,dy*inv,dz*inv,&shs[tid*16]);
      }
    }
    __syncthreads();
    for(int t=tid;t<cnt*35;t+=TB){
      int ee=t/35, r=t-ee*35, p=r/5, u=r-p*5;
      int sl=sl_[ee];
      if(sl>=0){
        int l1=(p+1)>>1;                         // 0,1,1,2,2,3,3
        int l2=(0x3636>>(2*p))&3;                // 2,1,3,0,2,1,3
        const unsigned long long wbpack=
          (25ULL<<9)|(70ULL<<18)|(175ULL<<27)|(200ULL<<36)|(325ULL<<45)|(430ULL<<54);
        int wb=(int)((wbpack>>(9*p))&511ULL);    // 0,25,70,175,200,325,430
        int n1=2*l1+1, n2=2*l2+1;
        float tu=tp2s[p*5+u];
        float o0=0.f,o1=0.f,o2=0.f,o3=0.f,o4=0.f;
        float* mrow=&nmid_g[sl*80+5*l1*l1+u*n1];
        const float* shrow=&shs[ee*16+l2*l2];
        const float* Wp=&w3s[wb];
        for(int i=0;i<n1;i++){
          float mi=cloadf(&mrow[i])*tu;          // coherent: produced by other blocks' atomics
          for(int j=0;j<n2;j++){
            float c=mi*shrow[j];
            const float* Wk=Wp+(i*n2+j)*5;
            o0+=Wk[0]*c; o1+=Wk[1]*c; o2+=Wk[2]*c; o3+=Wk[3]*c; o4+=Wk[4]*c;
          }
        }
        atomicAdd(&acc[0],o0); atomicAdd(&acc[1],o1); atomicAdd(&acc[2],o2);
        atomicAdd(&acc[3],o3); atomicAdd(&acc[4],o4);
      }
    }
    __syncthreads();
  }
  __syncthreads();
  const float scale=0.37796447300922725f*0.4082482904638631f;  // ALPHA2 * 1/sqrt(6)
  if(tid<5) out5[tid]=acc[tid]*scale;                          // end-of-kernel flush covers this
}

// ====================== launch ======================
extern "C" void kernel_launch(void* const* d_in, const int* in_sizes, int n_in,
                              void* d_out, int out_size, void* d_ws, size_t ws_size,
                              hipStream_t stream){
  const float* x    =(const float*)d_in[0];
  const float* pos  =(const float*)d_in[1];
  const int*   efrom=(const int*)  d_in[2];
  const int*   eto  =(const int*)  d_in[3];
  const float* W1   =(const float*)d_in[4];
  const float* W2   =(const float*)d_in[5];
  const float* tp2  =(const float*)d_in[6];
  int N=in_sizes[0], E=in_sizes[2];

  char* ws=(char*)d_ws;
  size_t o=0;
  unsigned long long* packed=(unsigned long long*)(ws+o); o+=8;
  int* numS=(int*)(ws+o);                   o+=4;
  int* numM=(int*)(ws+o);                   o+=4;
  int* bars=(int*)(ws+o);                   o+=8*4;
  size_t ctrl=o;                            // only this prefix needs host-side zeroing
  o=(o+63)&~(size_t)63;
  int* counts=(int*)(ws+o);                 o+=(size_t)N*4;
  int* S=(int*)(ws+o);                      o+=(size_t)CAP_S*4;
  int* M=(int*)(ws+o);                      o+=(size_t)CAP_M*4;
  float* nmid_g=(float*)(ws+o);             o+=(size_t)CAP_T*80*4;

  (void)hipMemsetAsync(d_ws,0,ctrl,stream); // 48 B: barrier counters + control words

  k_mega<<<NB,TB,0,stream>>>(x,pos,efrom,eto,W1,W2,tp2,N,E,
                             counts,packed,numS,numM,
                             S,M,nmid_g,bars,g_w3j,(float*)d_out);
}

// Round 8
// 141.310 us; speedup vs baseline: 2.1578x; 1.1797x over previous
//
#include <hip/hip_runtime.h>
#include <cmath>
#include <complex>
#include <algorithm>

#define NB    64    // persistent blocks (barrier arrivals are serialized same-line RMWs: fewer = faster)
#define TB    1024
#define CAP_S 512   // max edges out of Co (out-degree ~Poisson(12))
#define CAP_T 64    // max distinct targets of Co's edges
#define CAP_Q 256   // per-block LDS hit queue for merged scan+tail phase
#define EB    64    // per-batch edges staged in LDS in tail phases

// ====================== host-side Wigner 3j (exact port, runs at .so load) =====================
namespace w3jhost {
static double fact(int n){
  static const double f[13]={1,1,2,6,24,120,720,5040,40320,362880,3628800,39916800,479001600};
  return f[n];
}
static double su2_cg(int j1,int m1,int j2,int m2,int j3,int m3){
  if(m3!=m1+m2) return 0.0;
  int vmin = std::max(std::max(-j1+j2+m3,-j1+m1),0);
  int vmax = std::min(std::min(j2+j3+m1, j3-j1+j2), j3+m3);
  double C = std::sqrt((double)(2*j3+1)*fact(j3+j1-j2)*fact(j3-j1+j2)*fact(j1+j2-j3)*fact(j3+m3)*fact(j3-m3)
            /(fact(j1+j2+j3+1)*fact(j1-m1)*fact(j1+m1)*fact(j2-m2)*fact(j2+m2)));
  double S=0.0;
  for(int v=vmin;v<=vmax;v++){
    double sgn = ((v+j2+m2)&1)?-1.0:1.0;
    S += sgn/fact(v)*fact(j2+j3+m1-v)*fact(j1-m1+v)/fact(j3-j1+j2-v)/fact(j3+m3-v)/fact(v+j1-j2-m3);
  }
  return C*S;
}
static void real_basis(int l, std::complex<double> q[7][7]){
  for(int i=0;i<7;i++)for(int j=0;j<7;j++) q[i][j]=0.0;
  const double r = std::sqrt(0.5);
  for(int m=-l;m<0;m++){ q[l+m][l-m]=r; q[l+m][l+m]=std::complex<double>(0.0,-r); }
  q[l][l]=1.0;
  for(int m=1;m<=l;m++){ double sg=(m&1)?-1.0:1.0; q[l+m][l+m]=sg*r; q[l+m][l-m]=std::complex<double>(0.0,sg*r); }
  std::complex<double> f;
  switch(l&3){ case 0: f={1,0};break; case 1: f={0,-1};break; case 2: f={-1,0};break; default: f={0,1};break; }
  for(int i=0;i<7;i++)for(int j=0;j<7;j++) q[i][j]*=f;
}
} // namespace w3jhost

struct W3JArg { float w[675]; };  // 7 paths concatenated, layout [i*(2l2+1)+j]*5+k

static W3JArg compute_w3j(){
  using namespace w3jhost;
  W3JArg out{};
  const int pl1[7]={0,1,1,2,2,3,3}, pl2[7]={2,1,3,0,2,1,3};
  int off=0;
  for(int p=0;p<7;p++){
    int l1=pl1[p], l2=pl2[p], l3=2;
    int n1=2*l1+1, n2=2*l2+1, n3=2*l3+1;
    double C[7][7][5];
    for(int i=0;i<7;i++)for(int k=0;k<7;k++)for(int n=0;n<5;n++) C[i][k][n]=0.0;
    for(int m1=-l1;m1<=l1;m1++)for(int m2=-l2;m2<=l2;m2++)
      if(std::abs(m1+m2)<=l3) C[l1+m1][l2+m2][l3+m1+m2]=su2_cg(l1,m1,l2,m2,l3,m1+m2);
    std::complex<double> Q1[7][7],Q2[7][7],Q3[7][7];
    real_basis(l1,Q1); real_basis(l2,Q2); real_basis(l3,Q3);
    double Cr[7][7][5]; double nrm=0.0;
    for(int a=0;a<n1;a++)for(int b=0;b<n2;b++)for(int c=0;c<n3;c++){
      std::complex<double> s(0.0,0.0);
      for(int i=0;i<n1;i++)for(int k=0;k<n2;k++)for(int n=0;n<n3;n++){
        double cv=C[i][k][n]; if(cv==0.0) continue;
        s += Q1[i][a]*Q2[k][b]*std::conj(Q3[n][c])*cv;  // einsum 'ij,kl,mn,ikn->jlm'
      }
      Cr[a][b][c]=s.real(); nrm+=s.real()*s.real();
    }
    nrm=std::sqrt(nrm);
    for(int a=0;a<n1;a++)for(int b=0;b<n2;b++)for(int c=0;c<n3;c++)
      out.w[off+(a*n2+b)*n3+c]=(float)(Cr[a][b][c]/nrm);
    off+=n1*n2*n3;
  }
  return out;
}
static const W3JArg g_w3j = compute_w3j();  // constant data; same every call

// ====================== device helpers ======================
__device__ __forceinline__ void calc_sh(float x,float y,float z,float* sh){
  float x2=x*x,y2=y*y,z2=z*z;
  const float s3=1.7320508075688772f, s5=2.2360679774997896f, s15=3.872983346207417f;
  const float s70_4=2.091650066335189f, s105=10.246950765959598f, s42_4=1.6201851746019651f;
  const float s7_2=1.3228756555322954f, s105_2=5.123475382979799f;
  sh[0]=1.f;
  sh[1]=s3*x; sh[2]=s3*y; sh[3]=s3*z;
  sh[4]=s15*x*z; sh[5]=s15*x*y; sh[6]=s5*(y2-0.5f*(x2+z2)); sh[7]=s15*y*z; sh[8]=0.5f*s15*(z2-x2);
  sh[9]=s70_4*x*(3.f*z2-x2); sh[10]=s105*x*y*z; sh[11]=s42_4*x*(5.f*y2-1.f);
  sh[12]=s7_2*y*(5.f*y2-3.f); sh[13]=s42_4*z*(5.f*y2-1.f); sh[14]=s105_2*y*(z2-x2); sh[15]=s70_4*z*(z2-3.f*x2);
}

// explicitly-coherent (agent-scope) scalar accesses: bypass the non-coherent
// per-XCD caches so NO L2 writeback/invalidate fences are needed anywhere.
__device__ __forceinline__ void cstore(int* p,int v){ __hip_atomic_store(p,v,__ATOMIC_RELAXED,__HIP_MEMORY_SCOPE_AGENT); }
__device__ __forceinline__ int  cload(const int* p){ return __hip_atomic_load(p,__ATOMIC_RELAXED,__HIP_MEMORY_SCOPE_AGENT); }
__device__ __forceinline__ float cloadf(const float* p){ return __hip_atomic_load(p,__ATOMIC_RELAXED,__HIP_MEMORY_SCOPE_AGENT); }

// FENCE-FREE grid barrier (r7: removing __threadfence saved 137us — wbl2/inv walks).
// All cross-block data moves via agent-scope atomics/stores, so the barrier only
// needs: drain my outstanding memory ops, then count arrivals.
__device__ __forceinline__ void gridbar(int* ctr){
  __syncthreads();
  if(threadIdx.x==0){
    asm volatile("s_waitcnt vmcnt(0) lgkmcnt(0)" ::: "memory");
    __hip_atomic_fetch_add(ctr,1,__ATOMIC_RELAXED,__HIP_MEMORY_SCOPE_AGENT);
    int it=0;
    while(__hip_atomic_load(ctr,__ATOMIC_RELAXED,__HIP_MEMORY_SCOPE_AGENT)<NB){
      if(it<16) __builtin_amdgcn_s_sleep(2);
      else      __builtin_amdgcn_s_sleep(16);
      ++it;
    }
  }
  __syncthreads();
}

// ====================== the persistent mega-kernel ======================
__global__ void __launch_bounds__(TB,1)
k_mega(const float* __restrict__ x, const float* __restrict__ pos,
       const int* __restrict__ efrom, const int* __restrict__ eto,
       const float* __restrict__ W1, const float* __restrict__ W2,
       const float* __restrict__ tp2, int N, int E,
       int* __restrict__ counts,
       unsigned long long* __restrict__ packed,
       int* __restrict__ numS,
       int* __restrict__ S, float* __restrict__ nmid_g,
       int* __restrict__ bars, W3JArg w3, float* __restrict__ out5){
  __shared__ float W1s[600];
  __shared__ float W2s[600];
  __shared__ float w3s[675];
  __shared__ float tp2s[35];
  __shared__ float shs[EB*16];
  __shared__ float embs[EB*20];
  __shared__ float hs[EB*30];
  __shared__ float tws[EB*20];
  __shared__ float es_[EB];
  __shared__ float dd_[EB];
  __shared__ int   sl_[EB];
  __shared__ int   Tlist[CAP_T];
  __shared__ int   Te[CAP_T];
  __shared__ int   Q[CAP_Q];
  __shared__ float acc[5];
  __shared__ unsigned long long bmax;
  __shared__ int   nTs, qn;

  const int tid=threadIdx.x;
  const int gtid=blockIdx.x*TB+tid;
  const int gstride=NB*TB;

  // ---- phase A: bincount + FUSED argmax via atomicAdd-return candidates ----
  // (counts/nmid/ctrl pre-zeroed by host memset; no in-kernel zero phase)
  if(tid==0){ bmax=0ull; }
  __syncthreads();
  {
    unsigned long long lm=0ull;
    int nQ_=(E+3)>>2;
    for(int q=gtid;q<nQ_;q+=gstride){
      int e=q*4;
      if(e+3<E){
        int4 v=*reinterpret_cast<const int4*>(eto+e);
        int c0=atomicAdd(&counts[v.x],1)+1;
        int c1=atomicAdd(&counts[v.y],1)+1;
        int c2=atomicAdd(&counts[v.z],1)+1;
        int c3=atomicAdd(&counts[v.w],1)+1;
        unsigned long long d0=(((unsigned long long)(unsigned)c0)<<32)|(unsigned long long)(0xFFFFFFFFu-(unsigned)v.x);
        unsigned long long d1=(((unsigned long long)(unsigned)c1)<<32)|(unsigned long long)(0xFFFFFFFFu-(unsigned)v.y);
        unsigned long long d2=(((unsigned long long)(unsigned)c2)<<32)|(unsigned long long)(0xFFFFFFFFu-(unsigned)v.z);
        unsigned long long d3=(((unsigned long long)(unsigned)c3)<<32)|(unsigned long long)(0xFFFFFFFFu-(unsigned)v.w);
        lm=max(max(max(max(lm,d0),d1),d2),d3);
      } else {
        for(;e<E;e++){
          int t=eto[e];
          int c=atomicAdd(&counts[t],1)+1;
          unsigned long long dd=(((unsigned long long)(unsigned)c)<<32)|(unsigned long long)(0xFFFFFFFFu-(unsigned)t);
          lm=max(lm,dd);
        }
      }
    }
    #pragma unroll
    for(int off=32;off;off>>=1){
      unsigned long long o=__shfl_xor(lm,off);
      lm=max(lm,o);
    }
    if((tid&63)==0) atomicMax(&bmax,lm);
    __syncthreads();
    if(tid==0) atomicMax(packed,bmax);
  }
  gridbar(&bars[0]);

  // ---- phase B: collect edges out of Co (coherent appends) ----
  {
    unsigned long long pk=__hip_atomic_load(packed,__ATOMIC_RELAXED,__HIP_MEMORY_SCOPE_AGENT);
    int co=(int)(0xFFFFFFFFu-(unsigned)(pk&0xFFFFFFFFull));   // numpy argmax (first max)
    int nQ_=(E+3)>>2;
    for(int q=gtid;q<nQ_;q+=gstride){
      int e=q*4;
      if(e+3<E){
        int4 v=*reinterpret_cast<const int4*>(efrom+e);
        int f[4]={v.x,v.y,v.z,v.w};
        #pragma unroll
        for(int k=0;k<4;k++){
          if(f[k]==co){
            int p=atomicAdd(numS,1);
            if(p<CAP_S) cstore(&S[p],e+k);
          }
        }
      } else {
        for(;e<E;e++){
          if(efrom[e]==co){
            int p=atomicAdd(numS,1);
            if(p<CAP_S) cstore(&S[p],e);
          }
        }
      }
    }
  }
  gridbar(&bars[1]);

  // ---- phase CD (merged): rebuild Tlist, scan efrom -> per-block LDS hit queue,
  //      then run the phased MLP pipeline on the local queue -> nmid atomics ----
  {
    int ns=cload(numS); if(ns>CAP_S) ns=CAP_S;
    int nsc=min(ns,CAP_T);   // dedup window (>= all realistic out-degrees)
    if(tid<nsc) Te[tid]=eto[cload(&S[tid])];
    if(tid==0) qn=0;
    // stage W1/W2 while Tlist settles
    for(int i=tid;i<600;i+=TB){ W1s[i]=W1[i]; W2s[i]=W2[i]; }
    __syncthreads();
    if(tid<64){              // wave 0: ballot-based dedup + prefix slots
      bool keep=false; int myv=0;
      if(tid<nsc){
        myv=Te[tid];
        keep=true;
        for(int k=0;k<tid;k++) if(Te[k]==myv){ keep=false; break; }
      }
      unsigned long long mask=__ballot(keep);
      if(keep){
        int slot=__popcll(mask&((1ull<<tid)-1ull));
        Tlist[slot]=myv;
      }
      if(tid==0) nTs=__popcll(mask);
    }
    __syncthreads();
    int nT=nTs;
    int nQ_=(E+3)>>2;
    for(int q=gtid;q<nQ_;q+=gstride){
      int e=q*4;
      if(e+3<E){
        int4 v=*reinterpret_cast<const int4*>(efrom+e);
        int hit0=0,hit1=0,hit2=0,hit3=0;
        for(int k=0;k<nT;k++){           // LDS broadcast reads: conflict-free
          int t=Tlist[k];
          hit0|=(v.x==t); hit1|=(v.y==t); hit2|=(v.z==t); hit3|=(v.w==t);
        }
        if(hit0){int p=atomicAdd(&qn,1); if(p<CAP_Q) Q[p]=e;  }
        if(hit1){int p=atomicAdd(&qn,1); if(p<CAP_Q) Q[p]=e+1;}
        if(hit2){int p=atomicAdd(&qn,1); if(p<CAP_Q) Q[p]=e+2;}
        if(hit3){int p=atomicAdd(&qn,1); if(p<CAP_Q) Q[p]=e+3;}
      } else {
        for(;e<E;e++){
          int s=efrom[e]; int hit=0;
          for(int k=0;k<nT;k++) hit|=(s==Tlist[k]);
          if(hit){int p=atomicAdd(&qn,1); if(p<CAP_Q) Q[p]=e;}
        }
      }
    }
    __syncthreads();
    int nq=qn; if(nq>CAP_Q) nq=CAP_Q;
    for(int base=0;base<nq;base+=EB){
      int cnt=min(EB,nq-base);
      // A0: per-edge meta + spherical harmonics (slot via Tlist search)
      if(tid<cnt){
        int e=Q[base+tid];
        int a=efrom[e];
        int sl=-1;
        for(int k=0;k<nT;k++) if(Tlist[k]==a){ sl=k; break; }
        sl_[tid]=sl;
        if(sl>=0){
          int b=eto[e];
          float dx=pos[3*b]-pos[3*a], dy=pos[3*b+1]-pos[3*a+1], dz=pos[3*b+2]-pos[3*a+2];
          float d=sqrtf(dx*dx+dy*dy+dz*dz);
          float inv=1.f/d;
          calc_sh(dx*inv,dy*inv,dz*inv,&shs[tid*16]);
          dd_[tid]=d;
          es_[tid]=x[b]*(0.18257418583505536f*0.4082482904638631f); // 1/sqrt30 * 1/sqrt6
        }
      }
      __syncthreads();
      // A1: radial embedding, one (edge,i) per task
      for(int t=tid;t<cnt*20;t+=TB){
        int ee=t/20, i=t-ee*20;
        if(sl_[ee]>=0){
          const float inv_step=21.f/3.5f;
          const float pref=(float)(1.14136*7.3890560989306495);  // 1.14136*e^2
          float di=dd_[ee]*inv_step;
          float A=di-(float)i, B=(float)(i+2)-di;
          float ua=(A>0.f)?expf(-1.f/A):0.f;
          float ub=(B>0.f)?expf(-1.f/B):0.f;
          embs[ee*20+i]=pref*ua*ub;
        }
      }
      __syncthreads();
      // B: MLP layer 1, one (edge,j) per task
      for(int t=tid;t<cnt*30;t+=TB){
        int ee=t/30, j=t-ee*30;
        if(sl_[ee]>=0){
          float z=0.f;
          #pragma unroll
          for(int i=0;i<20;i++) z+=embs[ee*20+i]*W1s[i*30+j];
          z*=0.22360679774997896f;                  // 1/sqrt20
          hs[ee*30+j]=1.679177f*z/(1.f+expf(-z));   // NORM2MOM * silu
        }
      }
      __syncthreads();
      // C: MLP layer 2, one (edge,c) per task
      for(int t=tid;t<cnt*20;t+=TB){
        int ee=t/20, c=t-ee*20;
        if(sl_[ee]>=0){
          float v=0.f;
          #pragma unroll
          for(int j=0;j<30;j++) v+=hs[ee*30+j]*W2s[j*20+c];
          tws[ee*20+c]=v;
        }
      }
      __syncthreads();
      // D: mid accumulation into GLOBAL nmid (device-scope atomics = coherent)
      for(int t=tid;t<cnt*80;t+=TB){
        int ee=t/80, oo=t-ee*80;
        int sl=sl_[ee];
        if(sl>=0){
          int l,u,mm;
          if(oo<5){ l=0; u=oo; mm=0; }
          else if(oo<20){ int r=oo-5;  l=1; u=r/3; mm=r-u*3; }
          else if(oo<45){ int r=oo-20; l=2; u=r/5; mm=r-u*5; }
          else          { int r=oo-45; l=3; u=r/7; mm=r-u*7; }
          float val=es_[ee]*tws[ee*20+l*5+u]*shs[ee*16+l*l+mm];
          atomicAdd(&nmid_g[sl*80+oo],val);
        }
      }
      __syncthreads();
    }
  }
  gridbar(&bars[2]);
  if(blockIdx.x!=0) return;

  // ---- phase E: second tensor product over edges out of Co (block 0 only) ----
  for(int i=tid;i<675;i+=TB) w3s[i]=w3.w[i];
  if(tid<35) tp2s[tid]=tp2[tid];
  if(tid<5) acc[tid]=0.f;
  int ns=cload(numS); if(ns>CAP_S) ns=CAP_S;
  int nT=nTs;
  for(int base=0;base<ns;base+=EB){
    int cnt=min(EB,ns-base);
    __syncthreads();
    if(tid<cnt){
      int e=cload(&S[base+tid]);
      int a=efrom[e], b=eto[e];
      int sl=-1;
      for(int k=0;k<nT;k++) if(Tlist[k]==b){ sl=k; break; }
      sl_[tid]=sl;
      if(sl>=0){
        float dx=pos[3*b]-pos[3*a], dy=pos[3*b+1]-pos[3*a+1], dz=pos[3*b+2]-pos[3*a+2];
        float d=sqrtf(dx*dx+dy*dy+dz*dz);
        float inv=1.f/d;
        calc_sh(dx*inv,dy*inv,dz*inv,&shs[tid*16]);
      }
    }
    __syncthreads();
    for(int t=tid;t<cnt*35;t+=TB){
      int ee=t/35, r=t-ee*35, p=r/5, u=r-p*5;
      int sl=sl_[ee];
      if(sl>=0){
        int l1=(p+1)>>1;                         // 0,1,1,2,2,3,3
        int l2=(0x3636>>(2*p))&3;                // 2,1,3,0,2,1,3
        const unsigned long long wbpack=
          (25ULL<<9)|(70ULL<<18)|(175ULL<<27)|(200ULL<<36)|(325ULL<<45)|(430ULL<<54);
        int wb=(int)((wbpack>>(9*p))&511ULL);    // 0,25,70,175,200,325,430
        int n1=2*l1+1, n2=2*l2+1;
        float tu=tp2s[p*5+u];
        float o0=0.f,o1=0.f,o2=0.f,o3=0.f,o4=0.f;
        float* mrow=&nmid_g[sl*80+5*l1*l1+u*n1];
        const float* shrow=&shs[ee*16+l2*l2];
        const float* Wp=&w3s[wb];
        for(int i=0;i<n1;i++){
          float mi=cloadf(&mrow[i])*tu;          // coherent: produced by other blocks' atomics
          for(int j=0;j<n2;j++){
            float c=mi*shrow[j];
            const float* Wk=Wp+(i*n2+j)*5;
            o0+=Wk[0]*c; o1+=Wk[1]*c; o2+=Wk[2]*c; o3+=Wk[3]*c; o4+=Wk[4]*c;
          }
        }
        atomicAdd(&acc[0],o0); atomicAdd(&acc[1],o1); atomicAdd(&acc[2],o2);
        atomicAdd(&acc[3],o3); atomicAdd(&acc[4],o4);
      }
    }
    __syncthreads();
  }
  __syncthreads();
  const float scale=0.37796447300922725f*0.4082482904638631f;  // ALPHA2 * 1/sqrt(6)
  if(tid<5) out5[tid]=acc[tid]*scale;                          // end-of-kernel flush covers this
}

// ====================== launch ======================
extern "C" void kernel_launch(void* const* d_in, const int* in_sizes, int n_in,
                              void* d_out, int out_size, void* d_ws, size_t ws_size,
                              hipStream_t stream){
  const float* x    =(const float*)d_in[0];
  const float* pos  =(const float*)d_in[1];
  const int*   efrom=(const int*)  d_in[2];
  const int*   eto  =(const int*)  d_in[3];
  const float* W1   =(const float*)d_in[4];
  const float* W2   =(const float*)d_in[5];
  const float* tp2  =(const float*)d_in[6];
  int N=in_sizes[0], E=in_sizes[2];

  char* ws=(char*)d_ws;
  size_t o=0;
  unsigned long long* packed=(unsigned long long*)(ws+o); o+=8;
  int* numS=(int*)(ws+o);                   o+=4;
  o+=4; // pad
  int* bars=(int*)(ws+o);                   o+=4*4;
  o=(o+63)&~(size_t)63;
  int* counts=(int*)(ws+o);                 o+=(size_t)N*4;
  float* nmid_g=(float*)(ws+o);             o+=(size_t)CAP_T*80*4;
  size_t zlen=o;                            // contiguous zero region: ctrl+counts+nmid
  int* S=(int*)(ws+o);                      o+=(size_t)CAP_S*4;

  (void)hipMemsetAsync(d_ws,0,zlen,stream); // ~221 KB contiguous (replaces in-kernel zero phase)

  k_mega<<<NB,TB,0,stream>>>(x,pos,efrom,eto,W1,W2,tp2,N,E,
                             counts,packed,numS,
                             S,nmid_g,bars,g_w3j,(float*)d_out);
}

// Round 9
// 116.566 us; speedup vs baseline: 2.6159x; 1.2123x over previous
//
#include <hip/hip_runtime.h>
#include <cmath>
#include <complex>
#include <algorithm>

#define NB    32    // persistent blocks
#define NBH   16    // blocks that build LDS histograms in phase A
#define TB    1024
#define CAP_S 512   // max edges out of Co (out-degree ~Poisson(12))
#define CAP_T 64    // max distinct targets of Co's edges
#define CAP_Q 256   // per-block LDS hit queue for merged scan+tail phase
#define EB    64    // per-batch edges staged in LDS in tail phases
#define HW_MAX 12544  // hist words cap: supports N <= 50176 (N=50000 here)
#define BM_MAX 1568   // bitmap words cap: N <= 50176

// ====================== host-side Wigner 3j (exact port, runs at .so load) =====================
namespace w3jhost {
static double fact(int n){
  static const double f[13]={1,1,2,6,24,120,720,5040,40320,362880,3628800,39916800,479001600};
  return f[n];
}
static double su2_cg(int j1,int m1,int j2,int m2,int j3,int m3){
  if(m3!=m1+m2) return 0.0;
  int vmin = std::max(std::max(-j1+j2+m3,-j1+m1),0);
  int vmax = std::min(std::min(j2+j3+m1, j3-j1+j2), j3+m3);
  double C = std::sqrt((double)(2*j3+1)*fact(j3+j1-j2)*fact(j3-j1+j2)*fact(j1+j2-j3)*fact(j3+m3)*fact(j3-m3)
            /(fact(j1+j2+j3+1)*fact(j1-m1)*fact(j1+m1)*fact(j2-m2)*fact(j2+m2)));
  double S=0.0;
  for(int v=vmin;v<=vmax;v++){
    double sgn = ((v+j2+m2)&1)?-1.0:1.0;
    S += sgn/fact(v)*fact(j2+j3+m1-v)*fact(j1-m1+v)/fact(j3-j1+j2-v)/fact(j3+m3-v)/fact(v+j1-j2-m3);
  }
  return C*S;
}
static void real_basis(int l, std::complex<double> q[7][7]){
  for(int i=0;i<7;i++)for(int j=0;j<7;j++) q[i][j]=0.0;
  const double r = std::sqrt(0.5);
  for(int m=-l;m<0;m++){ q[l+m][l-m]=r; q[l+m][l+m]=std::complex<double>(0.0,-r); }
  q[l][l]=1.0;
  for(int m=1;m<=l;m++){ double sg=(m&1)?-1.0:1.0; q[l+m][l+m]=sg*r; q[l+m][l-m]=std::complex<double>(0.0,sg*r); }
  std::complex<double> f;
  switch(l&3){ case 0: f={1,0};break; case 1: f={0,-1};break; case 2: f={-1,0};break; default: f={0,1};break; }
  for(int i=0;i<7;i++)for(int j=0;j<7;j++) q[i][j]*=f;
}
} // namespace w3jhost

struct W3JArg { float w[675]; };  // 7 paths concatenated, layout [i*(2l2+1)+j]*5+k

static W3JArg compute_w3j(){
  using namespace w3jhost;
  W3JArg out{};
  const int pl1[7]={0,1,1,2,2,3,3}, pl2[7]={2,1,3,0,2,1,3};
  int off=0;
  for(int p=0;p<7;p++){
    int l1=pl1[p], l2=pl2[p], l3=2;
    int n1=2*l1+1, n2=2*l2+1, n3=2*l3+1;
    double C[7][7][5];
    for(int i=0;i<7;i++)for(int k=0;k<7;k++)for(int n=0;n<5;n++) C[i][k][n]=0.0;
    for(int m1=-l1;m1<=l1;m1++)for(int m2=-l2;m2<=l2;m2++)
      if(std::abs(m1+m2)<=l3) C[l1+m1][l2+m2][l3+m1+m2]=su2_cg(l1,m1,l2,m2,l3,m1+m2);
    std::complex<double> Q1[7][7],Q2[7][7],Q3[7][7];
    real_basis(l1,Q1); real_basis(l2,Q2); real_basis(l3,Q3);
    double Cr[7][7][5]; double nrm=0.0;
    for(int a=0;a<n1;a++)for(int b=0;b<n2;b++)for(int c=0;c<n3;c++){
      std::complex<double> s(0.0,0.0);
      for(int i=0;i<n1;i++)for(int k=0;k<n2;k++)for(int n=0;n<n3;n++){
        double cv=C[i][k][n]; if(cv==0.0) continue;
        s += Q1[i][a]*Q2[k][b]*std::conj(Q3[n][c])*cv;  // einsum 'ij,kl,mn,ikn->jlm'
      }
      Cr[a][b][c]=s.real(); nrm+=s.real()*s.real();
    }
    nrm=std::sqrt(nrm);
    for(int a=0;a<n1;a++)for(int b=0;b<n2;b++)for(int c=0;c<n3;c++)
      out.w[off+(a*n2+b)*n3+c]=(float)(Cr[a][b][c]/nrm);
    off+=n1*n2*n3;
  }
  return out;
}
static const W3JArg g_w3j = compute_w3j();  // constant data; same every call

// ====================== device helpers ======================
__device__ __forceinline__ void calc_sh(float x,float y,float z,float* sh){
  float x2=x*x,y2=y*y,z2=z*z;
  const float s3=1.7320508075688772f, s5=2.2360679774997896f, s15=3.872983346207417f;
  const float s70_4=2.091650066335189f, s105=10.246950765959598f, s42_4=1.6201851746019651f;
  const float s7_2=1.3228756555322954f, s105_2=5.123475382979799f;
  sh[0]=1.f;
  sh[1]=s3*x; sh[2]=s3*y; sh[3]=s3*z;
  sh[4]=s15*x*z; sh[5]=s15*x*y; sh[6]=s5*(y2-0.5f*(x2+z2)); sh[7]=s15*y*z; sh[8]=0.5f*s15*(z2-x2);
  sh[9]=s70_4*x*(3.f*z2-x2); sh[10]=s105*x*y*z; sh[11]=s42_4*x*(5.f*y2-1.f);
  sh[12]=s7_2*y*(5.f*y2-3.f); sh[13]=s42_4*z*(5.f*y2-1.f); sh[14]=s105_2*y*(z2-x2); sh[15]=s70_4*z*(z2-3.f*x2);
}

// explicitly-coherent (agent-scope) scalar accesses: bypass the non-coherent
// per-XCD caches so NO L2 writeback/invalidate fences are needed anywhere.
__device__ __forceinline__ void cstore(int* p,int v){ __hip_atomic_store(p,v,__ATOMIC_RELAXED,__HIP_MEMORY_SCOPE_AGENT); }
__device__ __forceinline__ int  cload(const int* p){ return __hip_atomic_load(p,__ATOMIC_RELAXED,__HIP_MEMORY_SCOPE_AGENT); }
__device__ __forceinline__ void cstoref(float* p,float v){ __hip_atomic_store(p,v,__ATOMIC_RELAXED,__HIP_MEMORY_SCOPE_AGENT); }
__device__ __forceinline__ float cloadf(const float* p){ return __hip_atomic_load(p,__ATOMIC_RELAXED,__HIP_MEMORY_SCOPE_AGENT); }

// FENCE-FREE grid barrier (r7: removing __threadfence saved 137us — wbl2/inv walks).
__device__ __forceinline__ void gridbar(int* ctr){
  __syncthreads();
  if(threadIdx.x==0){
    asm volatile("s_waitcnt vmcnt(0) lgkmcnt(0)" ::: "memory");
    __hip_atomic_fetch_add(ctr,1,__ATOMIC_RELAXED,__HIP_MEMORY_SCOPE_AGENT);
    int it=0;
    while(__hip_atomic_load(ctr,__ATOMIC_RELAXED,__HIP_MEMORY_SCOPE_AGENT)<NB){
      if(it<16) __builtin_amdgcn_s_sleep(2);
      else      __builtin_amdgcn_s_sleep(16);
      ++it;
    }
  }
  __syncthreads();
}

// ====================== the persistent mega-kernel ======================
__global__ void __launch_bounds__(TB,1)
k_mega(const float* __restrict__ x, const float* __restrict__ pos,
       const int* __restrict__ efrom, const int* __restrict__ eto,
       const float* __restrict__ W1, const float* __restrict__ W2,
       const float* __restrict__ tp2, int N, int E,
       int* __restrict__ histg,
       unsigned long long* __restrict__ packed,
       int* __restrict__ numS,
       int* __restrict__ S, float* __restrict__ nmid_g,
       int* __restrict__ bars, W3JArg w3, float* __restrict__ out5){
  // big LDS union: phase A uses the byte-packed histogram; CD/E use the pipeline arrays
  __shared__ union LdsU {
    int hist[HW_MAX];                    // 4x8-bit counters per word (max in-degree ~35 << 255)
    struct {
      float W1s[600], W2s[600];
      float shs[EB*16], embs[EB*20], hs[EB*30], tws[EB*20];
      float es_[EB], dd_[EB];
      float nmid_s[CAP_T*80];            // phase E staging of nmid
      float w3s[675];
    } t;
  } U;
  __shared__ int   bitmap[BM_MAX];       // CD scan: node-membership bitmap
  __shared__ int   sl_[EB];
  __shared__ int   Tlist[CAP_T];
  __shared__ int   Te[CAP_T];
  __shared__ int   Q[CAP_Q];
  __shared__ float tp2s[35];
  __shared__ float acc[5];
  __shared__ unsigned long long bmax;
  __shared__ int   nTs, qn;

  const int tid=threadIdx.x;
  const int gtid=blockIdx.x*TB+tid;
  const int gstride=NB*TB;
  const int HW=(N+3)>>2;                 // 12500 for N=50000 (<= HW_MAX by construction)

  // ---- phase A: LDS byte-packed histogram bincount (NO scattered global atomics) ----
  for(int i=gtid;i<CAP_T*80;i+=gstride) cstoref(&nmid_g[i],0.f);   // zero nmid in-kernel
  if(blockIdx.x<NBH){
    for(int w=tid;w<HW;w+=TB) U.hist[w]=0;
    __syncthreads();
    int nQ_=(E+3)>>2;
    for(int q=blockIdx.x*TB+tid;q<nQ_;q+=NBH*TB){
      int e=q*4;
      if(e+3<E){
        int4 v=*reinterpret_cast<const int4*>(eto+e);
        atomicAdd(&U.hist[v.x>>2], 1<<((v.x&3)*8));
        atomicAdd(&U.hist[v.y>>2], 1<<((v.y&3)*8));
        atomicAdd(&U.hist[v.z>>2], 1<<((v.z&3)*8));
        atomicAdd(&U.hist[v.w>>2], 1<<((v.w&3)*8));
      } else {
        for(;e<E;e++){ int t=eto[e]; atomicAdd(&U.hist[t>>2], 1<<((t&3)*8)); }
      }
    }
    __syncthreads();
    // coalesced coherent writeout of this block's histogram region
    for(int w=tid;w<HW;w+=TB) cstore(&histg[blockIdx.x*HW+w], U.hist[w]);
  }
  if(tid==0) bmax=0ull;
  gridbar(&bars[0]);

  // ---- phase A2: merge NBH histograms + argmax ----
  {
    unsigned long long lm=0ull;
    for(int w=gtid;w<HW;w+=gstride){
      int c0=0,c1=0,c2=0,c3=0;
      for(int b=0;b<NBH;b++){
        int h=cload(&histg[b*HW+w]);
        c0+=h&255; c1+=(h>>8)&255; c2+=(h>>16)&255; c3+=((unsigned)h>>24);
      }
      int node=w*4;
      unsigned long long d;
      if(node  <N&&c0>0){ d=(((unsigned long long)(unsigned)c0)<<32)|(unsigned long long)(0xFFFFFFFFu-(unsigned)(node  )); lm=max(lm,d); }
      if(node+1<N&&c1>0){ d=(((unsigned long long)(unsigned)c1)<<32)|(unsigned long long)(0xFFFFFFFFu-(unsigned)(node+1)); lm=max(lm,d); }
      if(node+2<N&&c2>0){ d=(((unsigned long long)(unsigned)c2)<<32)|(unsigned long long)(0xFFFFFFFFu-(unsigned)(node+2)); lm=max(lm,d); }
      if(node+3<N&&c3>0){ d=(((unsigned long long)(unsigned)c3)<<32)|(unsigned long long)(0xFFFFFFFFu-(unsigned)(node+3)); lm=max(lm,d); }
    }
    #pragma unroll
    for(int off=32;off;off>>=1){
      unsigned long long o=__shfl_xor(lm,off);
      lm=max(lm,o);
    }
    if((tid&63)==0) atomicMax(&bmax,lm);
    __syncthreads();
    if(tid==0) atomicMax(packed,bmax);
  }
  gridbar(&bars[1]);

  // ---- phase B: collect edges out of Co (coherent appends) ----
  {
    unsigned long long pk=__hip_atomic_load(packed,__ATOMIC_RELAXED,__HIP_MEMORY_SCOPE_AGENT);
    int co=(int)(0xFFFFFFFFu-(unsigned)(pk&0xFFFFFFFFull));   // numpy argmax (first max)
    int nQ_=(E+3)>>2;
    for(int q=gtid;q<nQ_;q+=gstride){
      int e=q*4;
      if(e+3<E){
        int4 v=*reinterpret_cast<const int4*>(efrom+e);
        int f[4]={v.x,v.y,v.z,v.w};
        #pragma unroll
        for(int k=0;k<4;k++){
          if(f[k]==co){
            int p=atomicAdd(numS,1);
            if(p<CAP_S) cstore(&S[p],e+k);
          }
        }
      } else {
        for(;e<E;e++){
          if(efrom[e]==co){
            int p=atomicAdd(numS,1);
            if(p<CAP_S) cstore(&S[p],e);
          }
        }
      }
    }
  }
  gridbar(&bars[2]);

  // ---- phase CD (merged): Tlist rebuild + bitmap scan -> per-block queue -> MLP tail ----
  {
    int ns=cload(numS); if(ns>CAP_S) ns=CAP_S;
    int nsc=min(ns,CAP_T);   // dedup window (>= all realistic out-degrees)
    if(tid<nsc) Te[tid]=eto[cload(&S[tid])];
    if(tid==0) qn=0;
    const int BMW=(N+31)>>5;
    for(int w=tid;w<BMW;w+=TB) bitmap[w]=0;
    // stage W1/W2 (hist union member is dead after bar0)
    for(int i=tid;i<600;i+=TB){ U.t.W1s[i]=W1[i]; U.t.W2s[i]=W2[i]; }
    __syncthreads();
    if(tid<64){              // wave 0: ballot-based dedup + prefix slots
      bool keep=false; int myv=0;
      if(tid<nsc){
        myv=Te[tid];
        keep=true;
        for(int k=0;k<tid;k++) if(Te[k]==myv){ keep=false; break; }
      }
      unsigned long long mask=__ballot(keep);
      if(keep){
        int slot=__popcll(mask&((1ull<<tid)-1ull));
        Tlist[slot]=myv;
      }
      if(tid==0) nTs=__popcll(mask);
    }
    __syncthreads();
    int nT=nTs;
    if(tid<nT){ int v=Tlist[tid]; atomicOr(&bitmap[v>>5], 1<<(v&31)); }
    __syncthreads();
    int nQ_=(E+3)>>2;
    for(int q=gtid;q<nQ_;q+=gstride){
      int e=q*4;
      if(e+3<E){
        int4 v=*reinterpret_cast<const int4*>(efrom+e);
        int h0=(bitmap[v.x>>5]>>(v.x&31))&1;
        int h1=(bitmap[v.y>>5]>>(v.y&31))&1;
        int h2=(bitmap[v.z>>5]>>(v.z&31))&1;
        int h3=(bitmap[v.w>>5]>>(v.w&31))&1;
        if(h0){int p=atomicAdd(&qn,1); if(p<CAP_Q) Q[p]=e;  }
        if(h1){int p=atomicAdd(&qn,1); if(p<CAP_Q) Q[p]=e+1;}
        if(h2){int p=atomicAdd(&qn,1); if(p<CAP_Q) Q[p]=e+2;}
        if(h3){int p=atomicAdd(&qn,1); if(p<CAP_Q) Q[p]=e+3;}
      } else {
        for(;e<E;e++){
          int s=efrom[e];
          if((bitmap[s>>5]>>(s&31))&1){int p=atomicAdd(&qn,1); if(p<CAP_Q) Q[p]=e;}
        }
      }
    }
    __syncthreads();
    int nq=qn; if(nq>CAP_Q) nq=CAP_Q;
    for(int base=0;base<nq;base+=EB){
      int cnt=min(EB,nq-base);
      // A0: per-edge meta + spherical harmonics (slot via Tlist search)
      if(tid<cnt){
        int e=Q[base+tid];
        int a=efrom[e];
        int sl=-1;
        for(int k=0;k<nT;k++) if(Tlist[k]==a){ sl=k; break; }
        sl_[tid]=sl;
        if(sl>=0){
          int b=eto[e];
          float dx=pos[3*b]-pos[3*a], dy=pos[3*b+1]-pos[3*a+1], dz=pos[3*b+2]-pos[3*a+2];
          float d=sqrtf(dx*dx+dy*dy+dz*dz);
          float inv=1.f/d;
          calc_sh(dx*inv,dy*inv,dz*inv,&U.t.shs[tid*16]);
          U.t.dd_[tid]=d;
          U.t.es_[tid]=x[b]*(0.18257418583505536f*0.4082482904638631f); // 1/sqrt30 * 1/sqrt6
        }
      }
      __syncthreads();
      // A1: radial embedding, one (edge,i) per task
      for(int t=tid;t<cnt*20;t+=TB){
        int ee=t/20, i=t-ee*20;
        if(sl_[ee]>=0){
          const float inv_step=21.f/3.5f;
          const float pref=(float)(1.14136*7.3890560989306495);  // 1.14136*e^2
          float di=U.t.dd_[ee]*inv_step;
          float A=di-(float)i, B=(float)(i+2)-di;
          float ua=(A>0.f)?expf(-1.f/A):0.f;
          float ub=(B>0.f)?expf(-1.f/B):0.f;
          U.t.embs[ee*20+i]=pref*ua*ub;
        }
      }
      __syncthreads();
      // B: MLP layer 1, one (edge,j) per task
      for(int t=tid;t<cnt*30;t+=TB){
        int ee=t/30, j=t-ee*30;
        if(sl_[ee]>=0){
          float z=0.f;
          #pragma unroll
          for(int i=0;i<20;i++) z+=U.t.embs[ee*20+i]*U.t.W1s[i*30+j];
          z*=0.22360679774997896f;                  // 1/sqrt20
          U.t.hs[ee*30+j]=1.679177f*z/(1.f+expf(-z));   // NORM2MOM * silu
        }
      }
      __syncthreads();
      // C: MLP layer 2, one (edge,c) per task
      for(int t=tid;t<cnt*20;t+=TB){
        int ee=t/20, c=t-ee*20;
        if(sl_[ee]>=0){
          float v=0.f;
          #pragma unroll
          for(int j=0;j<30;j++) v+=U.t.hs[ee*30+j]*U.t.W2s[j*20+c];
          U.t.tws[ee*20+c]=v;
        }
      }
      __syncthreads();
      // D: mid accumulation into GLOBAL nmid (device-scope atomics = coherent)
      for(int t=tid;t<cnt*80;t+=TB){
        int ee=t/80, oo=t-ee*80;
        int sl=sl_[ee];
        if(sl>=0){
          int l,u,mm;
          if(oo<5){ l=0; u=oo; mm=0; }
          else if(oo<20){ int r=oo-5;  l=1; u=r/3; mm=r-u*3; }
          else if(oo<45){ int r=oo-20; l=2; u=r/5; mm=r-u*5; }
          else          { int r=oo-45; l=3; u=r/7; mm=r-u*7; }
          float val=U.t.es_[ee]*U.t.tws[ee*20+l*5+u]*U.t.shs[ee*16+l*l+mm];
          atomicAdd(&nmid_g[sl*80+oo],val);
        }
      }
      __syncthreads();
    }
  }
  gridbar(&bars[3]);
  if(blockIdx.x!=0) return;

  // ---- phase E: second tensor product over edges out of Co (block 0 only) ----
  for(int i=tid;i<675;i+=TB) U.t.w3s[i]=w3.w[i];
  if(tid<35) tp2s[tid]=tp2[tid];
  if(tid<5) acc[tid]=0.f;
  int ns=cload(numS); if(ns>CAP_S) ns=CAP_S;
  int nT=nTs;
  // stage nmid into LDS ONCE (coherent loads), so inner tasks read LDS not MALL
  for(int i=tid;i<nT*80;i+=TB) U.t.nmid_s[i]=cloadf(&nmid_g[i]);
  for(int base=0;base<ns;base+=EB){
    int cnt=min(EB,ns-base);
    __syncthreads();
    if(tid<cnt){
      int e=cload(&S[base+tid]);
      int a=efrom[e], b=eto[e];
      int sl=-1;
      for(int k=0;k<nT;k++) if(Tlist[k]==b){ sl=k; break; }
      sl_[tid]=sl;
      if(sl>=0){
        float dx=pos[3*b]-pos[3*a], dy=pos[3*b+1]-pos[3*a+1], dz=pos[3*b+2]-pos[3*a+2];
        float d=sqrtf(dx*dx+dy*dy+dz*dz);
        float inv=1.f/d;
        calc_sh(dx*inv,dy*inv,dz*inv,&U.t.shs[tid*16]);
      }
    }
    __syncthreads();
    for(int t=tid;t<cnt*35;t+=TB){
      int ee=t/35, r=t-ee*35, p=r/5, u=r-p*5;
      int sl=sl_[ee];
      if(sl>=0){
        int l1=(p+1)>>1;                         // 0,1,1,2,2,3,3
        int l2=(0x3636>>(2*p))&3;                // 2,1,3,0,2,1,3
        const unsigned long long wbpack=
          (25ULL<<9)|(70ULL<<18)|(175ULL<<27)|(200ULL<<36)|(325ULL<<45)|(430ULL<<54);
        int wb=(int)((wbpack>>(9*p))&511ULL);    // 0,25,70,175,200,325,430
        int n1=2*l1+1, n2=2*l2+1;
        float tu=tp2s[p*5+u];
        float o0=0.f,o1=0.f,o2=0.f,o3=0.f,o4=0.f;
        const float* mrow=&U.t.nmid_s[sl*80+5*l1*l1+u*n1];
        const float* shrow=&U.t.shs[ee*16+l2*l2];
        const float* Wp=&U.t.w3s[wb];
        for(int i=0;i<n1;i++){
          float mi=mrow[i]*tu;
          for(int j=0;j<n2;j++){
            float c=mi*shrow[j];
            const float* Wk=Wp+(i*n2+j)*5;
            o0+=Wk[0]*c; o1+=Wk[1]*c; o2+=Wk[2]*c; o3+=Wk[3]*c; o4+=Wk[4]*c;
          }
        }
        atomicAdd(&acc[0],o0); atomicAdd(&acc[1],o1); atomicAdd(&acc[2],o2);
        atomicAdd(&acc[3],o3); atomicAdd(&acc[4],o4);
      }
    }
    __syncthreads();
  }
  __syncthreads();
  const float scale=0.37796447300922725f*0.4082482904638631f;  // ALPHA2 * 1/sqrt(6)
  if(tid<5) out5[tid]=acc[tid]*scale;                          // end-of-kernel flush covers this
}

// ====================== launch ======================
extern "C" void kernel_launch(void* const* d_in, const int* in_sizes, int n_in,
                              void* d_out, int out_size, void* d_ws, size_t ws_size,
                              hipStream_t stream){
  const float* x    =(const float*)d_in[0];
  const float* pos  =(const float*)d_in[1];
  const int*   efrom=(const int*)  d_in[2];
  const int*   eto  =(const int*)  d_in[3];
  const float* W1   =(const float*)d_in[4];
  const float* W2   =(const float*)d_in[5];
  const float* tp2  =(const float*)d_in[6];
  int N=in_sizes[0], E=in_sizes[2];
  int HW=(N+3)>>2;

  char* ws=(char*)d_ws;
  size_t o=0;
  unsigned long long* packed=(unsigned long long*)(ws+o); o+=8;
  int* numS=(int*)(ws+o);                   o+=4;
  o+=4; // pad
  int* bars=(int*)(ws+o);                   o+=8*4;
  size_t ctrl=o;                            // 48 B control region (only this is memset)
  o=(o+63)&~(size_t)63;
  int* histg=(int*)(ws+o);                  o+=(size_t)NBH*HW*4;   // 800 KB
  int* S=(int*)(ws+o);                      o+=(size_t)CAP_S*4;
  float* nmid_g=(float*)(ws+o);             o+=(size_t)CAP_T*80*4;

  (void)hipMemsetAsync(d_ws,0,ctrl,stream); // control words only (hist/nmid handled in-kernel)

  k_mega<<<NB,TB,0,stream>>>(x,pos,efrom,eto,W1,W2,tp2,N,E,
                             histg,packed,numS,
                             S,nmid_g,bars,g_w3j,(float*)d_out);
}

// Round 10
// 114.246 us; speedup vs baseline: 2.6690x; 1.0203x over previous
//
#include <hip/hip_runtime.h>
#include <cmath>
#include <complex>
#include <algorithm>

#define NBH   16      // histogram blocks
#define CAP_S 512     // max edges out of Co (out-degree ~Poisson(12))
#define CAP_T 64      // max distinct targets of Co's edges
#define CAP_M 4096    // max edges whose source is a target of Co
#define EB    64      // per-batch edges staged in LDS in tail kernels
#define HW_MAX 12544  // hist words cap: N <= 50176 (N=50000 here)
#define BM_MAX 1568   // bitmap words cap: N <= 50176

// ====================== host-side Wigner 3j (exact port, runs at .so load) =====================
namespace w3jhost {
static double fact(int n){
  static const double f[13]={1,1,2,6,24,120,720,5040,40320,362880,3628800,39916800,479001600};
  return f[n];
}
static double su2_cg(int j1,int m1,int j2,int m2,int j3,int m3){
  if(m3!=m1+m2) return 0.0;
  int vmin = std::max(std::max(-j1+j2+m3,-j1+m1),0);
  int vmax = std::min(std::min(j2+j3+m1, j3-j1+j2), j3+m3);
  double C = std::sqrt((double)(2*j3+1)*fact(j3+j1-j2)*fact(j3-j1+j2)*fact(j1+j2-j3)*fact(j3+m3)*fact(j3-m3)
            /(fact(j1+j2+j3+1)*fact(j1-m1)*fact(j1+m1)*fact(j2-m2)*fact(j2+m2)));
  double S=0.0;
  for(int v=vmin;v<=vmax;v++){
    double sgn = ((v+j2+m2)&1)?-1.0:1.0;
    S += sgn/fact(v)*fact(j2+j3+m1-v)*fact(j1-m1+v)/fact(j3-j1+j2-v)/fact(j3+m3-v)/fact(v+j1-j2-m3);
  }
  return C*S;
}
static void real_basis(int l, std::complex<double> q[7][7]){
  for(int i=0;i<7;i++)for(int j=0;j<7;j++) q[i][j]=0.0;
  const double r = std::sqrt(0.5);
  for(int m=-l;m<0;m++){ q[l+m][l-m]=r; q[l+m][l+m]=std::complex<double>(0.0,-r); }
  q[l][l]=1.0;
  for(int m=1;m<=l;m++){ double sg=(m&1)?-1.0:1.0; q[l+m][l+m]=sg*r; q[l+m][l-m]=std::complex<double>(0.0,sg*r); }
  std::complex<double> f;
  switch(l&3){ case 0: f={1,0};break; case 1: f={0,-1};break; case 2: f={-1,0};break; default: f={0,1};break; }
  for(int i=0;i<7;i++)for(int j=0;j<7;j++) q[i][j]*=f;
}
} // namespace w3jhost

struct W3JArg { float w[675]; };  // 7 paths concatenated, layout [i*(2l2+1)+j]*5+k

static W3JArg compute_w3j(){
  using namespace w3jhost;
  W3JArg out{};
  const int pl1[7]={0,1,1,2,2,3,3}, pl2[7]={2,1,3,0,2,1,3};
  int off=0;
  for(int p=0;p<7;p++){
    int l1=pl1[p], l2=pl2[p], l3=2;
    int n1=2*l1+1, n2=2*l2+1, n3=2*l3+1;
    double C[7][7][5];
    for(int i=0;i<7;i++)for(int k=0;k<7;k++)for(int n=0;n<5;n++) C[i][k][n]=0.0;
    for(int m1=-l1;m1<=l1;m1++)for(int m2=-l2;m2<=l2;m2++)
      if(std::abs(m1+m2)<=l3) C[l1+m1][l2+m2][l3+m1+m2]=su2_cg(l1,m1,l2,m2,l3,m1+m2);
    std::complex<double> Q1[7][7],Q2[7][7],Q3[7][7];
    real_basis(l1,Q1); real_basis(l2,Q2); real_basis(l3,Q3);
    double Cr[7][7][5]; double nrm=0.0;
    for(int a=0;a<n1;a++)for(int b=0;b<n2;b++)for(int c=0;c<n3;c++){
      std::complex<double> s(0.0,0.0);
      for(int i=0;i<n1;i++)for(int k=0;k<n2;k++)for(int n=0;n<n3;n++){
        double cv=C[i][k][n]; if(cv==0.0) continue;
        s += Q1[i][a]*Q2[k][b]*std::conj(Q3[n][c])*cv;  // einsum 'ij,kl,mn,ikn->jlm'
      }
      Cr[a][b][c]=s.real(); nrm+=s.real()*s.real();
    }
    nrm=std::sqrt(nrm);
    for(int a=0;a<n1;a++)for(int b=0;b<n2;b++)for(int c=0;c<n3;c++)
      out.w[off+(a*n2+b)*n3+c]=(float)(Cr[a][b][c]/nrm);
    off+=n1*n2*n3;
  }
  return out;
}
static const W3JArg g_w3j = compute_w3j();  // constant data; same every call

// ====================== device helpers ======================
__device__ __forceinline__ void calc_sh(float x,float y,float z,float* sh){
  float x2=x*x,y2=y*y,z2=z*z;
  const float s3=1.7320508075688772f, s5=2.2360679774997896f, s15=3.872983346207417f;
  const float s70_4=2.091650066335189f, s105=10.246950765959598f, s42_4=1.6201851746019651f;
  const float s7_2=1.3228756555322954f, s105_2=5.123475382979799f;
  sh[0]=1.f;
  sh[1]=s3*x; sh[2]=s3*y; sh[3]=s3*z;
  sh[4]=s15*x*z; sh[5]=s15*x*y; sh[6]=s5*(y2-0.5f*(x2+z2)); sh[7]=s15*y*z; sh[8]=0.5f*s15*(z2-x2);
  sh[9]=s70_4*x*(3.f*z2-x2); sh[10]=s105*x*y*z; sh[11]=s42_4*x*(5.f*y2-1.f);
  sh[12]=s7_2*y*(5.f*y2-3.f); sh[13]=s42_4*z*(5.f*y2-1.f); sh[14]=s105_2*y*(z2-x2); sh[15]=s70_4*z*(z2-3.f*x2);
}

// ====================== k1: LDS byte-packed histogram of eto ======================
__global__ void __launch_bounds__(1024,1)
k_hist(const int* __restrict__ eto, int E, int N, int* __restrict__ histg){
  __shared__ int hist[HW_MAX];    // 4x8-bit counters/word (max in-degree ~35 << 255)
  const int HW=(N+3)>>2;
  const int tid=threadIdx.x;
  for(int w=tid;w<HW;w+=1024) hist[w]=0;
  __syncthreads();
  int nQ=(E+3)>>2;
  for(int q=blockIdx.x*1024+tid;q<nQ;q+=NBH*1024){
    int e=q*4;
    if(e+3<E){
      int4 v=*reinterpret_cast<const int4*>(eto+e);
      atomicAdd(&hist[v.x>>2], 1<<((v.x&3)*8));
      atomicAdd(&hist[v.y>>2], 1<<((v.y&3)*8));
      atomicAdd(&hist[v.z>>2], 1<<((v.z&3)*8));
      atomicAdd(&hist[v.w>>2], 1<<((v.w&3)*8));
    } else {
      for(;e<E;e++){ int t=eto[e]; atomicAdd(&hist[t>>2], 1<<((t&3)*8)); }
    }
  }
  __syncthreads();
  for(int w=tid;w<HW;w+=1024) histg[blockIdx.x*HW+w]=hist[w];   // coalesced
}

// ====================== k2: merge histograms + argmax ======================
__global__ void __launch_bounds__(256,1)
k_argmax(const int* __restrict__ histg, int N, unsigned long long* __restrict__ packed){
  const int HW=(N+3)>>2;
  int w=blockIdx.x*256+threadIdx.x;
  unsigned long long lm=0ull;
  if(w<HW){
    int c0=0,c1=0,c2=0,c3=0;
    #pragma unroll
    for(int b=0;b<NBH;b++){
      int h=histg[b*HW+w];                 // coalesced: consecutive tid -> consecutive w
      c0+=h&255; c1+=(h>>8)&255; c2+=(h>>16)&255; c3+=(int)((unsigned)h>>24);
    }
    int node=w*4;
    if(c0>0)          lm=max(lm,(((unsigned long long)(unsigned)c0)<<32)|(unsigned long long)(0xFFFFFFFFu-(unsigned)(node  )));
    if(node+1<N&&c1>0)lm=max(lm,(((unsigned long long)(unsigned)c1)<<32)|(unsigned long long)(0xFFFFFFFFu-(unsigned)(node+1)));
    if(node+2<N&&c2>0)lm=max(lm,(((unsigned long long)(unsigned)c2)<<32)|(unsigned long long)(0xFFFFFFFFu-(unsigned)(node+2)));
    if(node+3<N&&c3>0)lm=max(lm,(((unsigned long long)(unsigned)c3)<<32)|(unsigned long long)(0xFFFFFFFFu-(unsigned)(node+3)));
  }
  #pragma unroll
  for(int off=32;off;off>>=1){
    unsigned long long o=__shfl_xor(lm,off);
    lm=max(lm,o);
  }
  if((threadIdx.x&63)==0 && lm) atomicMax(packed,lm);
}

// ====================== k3: collect edges out of Co ======================
__global__ void __launch_bounds__(256,1)
k_collect(const int* __restrict__ efrom, int E,
          const unsigned long long* __restrict__ packed,
          int* __restrict__ S, int* __restrict__ numS){
  int co=(int)(0xFFFFFFFFu-(unsigned)((*packed)&0xFFFFFFFFull));  // numpy argmax (first max)
  int q=blockIdx.x*256+threadIdx.x;
  int e=q*4;
  if(e+3<E){
    int4 v=*reinterpret_cast<const int4*>(efrom+e);
    int f[4]={v.x,v.y,v.z,v.w};
    #pragma unroll
    for(int k=0;k<4;k++){
      if(f[k]==co){
        int p=atomicAdd(numS,1);
        if(p<CAP_S) S[p]=e+k;
      }
    }
  } else {
    for(;e<E;e++){
      if(efrom[e]==co){
        int p=atomicAdd(numS,1);
        if(p<CAP_S) S[p]=e;
      }
    }
  }
}

// ====================== k4: scan efrom for M-edges (bitmap + slot-packed append) ======================
__global__ void __launch_bounds__(256,1)
k_scanM(const int* __restrict__ efrom, const int* __restrict__ eto, int E, int N,
        const int* __restrict__ S, const int* __restrict__ numS,
        int* __restrict__ M, int* __restrict__ numM){
  __shared__ int bitmap[BM_MAX];
  __shared__ int Te[CAP_T];
  __shared__ int Tlist[CAP_T];
  __shared__ int nTs;
  const int tid=threadIdx.x;
  int ns=*numS; if(ns>CAP_S) ns=CAP_S;
  int nsc=min(ns,CAP_T);
  const int BMW=(N+31)>>5;
  for(int w=tid;w<BMW;w+=256) bitmap[w]=0;
  if(tid<nsc) Te[tid]=eto[S[tid]];
  __syncthreads();
  if(tid<64){   // wave 0: deterministic ballot dedup + prefix slots (same order as k6)
    bool keep=false; int myv=0;
    if(tid<nsc){
      myv=Te[tid];
      keep=true;
      for(int k=0;k<tid;k++) if(Te[k]==myv){ keep=false; break; }
    }
    unsigned long long mask=__ballot(keep);
    if(keep){
      int slot=__popcll(mask&((1ull<<tid)-1ull));
      Tlist[slot]=myv;
    }
    if(tid==0) nTs=__popcll(mask);
  }
  __syncthreads();
  int nT=nTs;
  if(tid<nT){ int v=Tlist[tid]; atomicOr(&bitmap[v>>5], 1<<(v&31)); }
  __syncthreads();
  int q=blockIdx.x*256+tid;
  int e=q*4;
  if(e+3<E){
    int4 v=*reinterpret_cast<const int4*>(efrom+e);
    int f[4]={v.x,v.y,v.z,v.w};
    #pragma unroll
    for(int k=0;k<4;k++){
      int s=f[k];
      if((bitmap[s>>5]>>(s&31))&1){
        int sl=0;
        for(int kk=0;kk<nT;kk++) if(Tlist[kk]==s){ sl=kk; break; }
        int p=atomicAdd(numM,1);
        if(p<CAP_M) M[p]=(e+k)|(sl<<20);   // e < 2^20 (E=600k); slot in bits 20..25
      }
    }
  } else {
    for(;e<E;e++){
      int s=efrom[e];
      if((bitmap[s>>5]>>(s&31))&1){
        int sl=0;
        for(int kk=0;kk<nT;kk++) if(Tlist[kk]==s){ sl=kk; break; }
        int p=atomicAdd(numM,1);
        if(p<CAP_M) M[p]=e|(sl<<20);
      }
    }
  }
}

// ====================== k5: per-M-edge radial MLP + sh -> nmid (task-parallel pipeline) ======================
__global__ void __launch_bounds__(1024,1)
k_mlp(const float* __restrict__ x, const float* __restrict__ pos,
      const int* __restrict__ efrom, const int* __restrict__ eto,
      const float* __restrict__ W1, const float* __restrict__ W2,
      const int* __restrict__ M, const int* __restrict__ numM,
      float* __restrict__ nmid_g){
  __shared__ float W1s[600], W2s[600];
  __shared__ float shs[EB*16], embs[EB*20], hs[EB*30], tws[EB*20];
  __shared__ float es_[EB], dd_[EB];
  __shared__ int   sl_[EB];
  const int tid=threadIdx.x;
  int nm=*numM; if(nm>CAP_M) nm=CAP_M;
  for(int i=tid;i<600;i+=1024){ W1s[i]=W1[i]; W2s[i]=W2[i]; }
  int nb=(int)gridDim.x;
  int per=(nm+nb-1)/nb;
  int lo=min(nm,(int)blockIdx.x*per), hi=min(nm,lo+per);
  for(int base=lo;base<hi;base+=EB){
    int cnt=min(EB,hi-base);
    __syncthreads();            // W1s ready (1st iter) + LDS reuse across batches
    if(tid<cnt){
      int m=M[base+tid];
      int e=m&0xFFFFF, sl=m>>20;
      sl_[tid]=sl;
      int a=efrom[e], b=eto[e];
      float dx=pos[3*b]-pos[3*a], dy=pos[3*b+1]-pos[3*a+1], dz=pos[3*b+2]-pos[3*a+2];
      float d=sqrtf(dx*dx+dy*dy+dz*dz);
      float inv=1.f/d;
      calc_sh(dx*inv,dy*inv,dz*inv,&shs[tid*16]);
      dd_[tid]=d;
      es_[tid]=x[b]*(0.18257418583505536f*0.4082482904638631f); // 1/sqrt30 * 1/sqrt6
    }
    __syncthreads();
    // radial embedding, one (edge,i) per task
    for(int t=tid;t<cnt*20;t+=1024){
      int ee=t/20, i=t-ee*20;
      const float inv_step=21.f/3.5f;
      const float pref=(float)(1.14136*7.3890560989306495);  // 1.14136*e^2
      float di=dd_[ee]*inv_step;
      float A=di-(float)i, B=(float)(i+2)-di;
      float ua=(A>0.f)?expf(-1.f/A):0.f;
      float ub=(B>0.f)?expf(-1.f/B):0.f;
      embs[ee*20+i]=pref*ua*ub;
    }
    __syncthreads();
    // MLP layer 1, one (edge,j) per task
    for(int t=tid;t<cnt*30;t+=1024){
      int ee=t/30, j=t-ee*30;
      float z=0.f;
      #pragma unroll
      for(int i=0;i<20;i++) z+=embs[ee*20+i]*W1s[i*30+j];
      z*=0.22360679774997896f;                  // 1/sqrt20
      hs[ee*30+j]=1.679177f*z/(1.f+expf(-z));   // NORM2MOM * silu
    }
    __syncthreads();
    // MLP layer 2, one (edge,c) per task
    for(int t=tid;t<cnt*20;t+=1024){
      int ee=t/20, c=t-ee*20;
      float v=0.f;
      #pragma unroll
      for(int j=0;j<30;j++) v+=hs[ee*30+j]*W2s[j*20+c];
      tws[ee*20+c]=v;
    }
    __syncthreads();
    // mid accumulation into global nmid, one (edge,out-of-80) per task
    for(int t=tid;t<cnt*80;t+=1024){
      int ee=t/80, oo=t-ee*80;
      int sl=sl_[ee];
      int l,u,mm;
      if(oo<5){ l=0; u=oo; mm=0; }
      else if(oo<20){ int r=oo-5;  l=1; u=r/3; mm=r-u*3; }
      else if(oo<45){ int r=oo-20; l=2; u=r/5; mm=r-u*5; }
      else          { int r=oo-45; l=3; u=r/7; mm=r-u*7; }
      float val=es_[ee]*tws[ee*20+l*5+u]*shs[ee*16+l*l+mm];
      atomicAdd(&nmid_g[sl*80+oo],val);
    }
  }
}

// ====================== k6: second tensor product + output (1 block) ======================
__global__ void __launch_bounds__(1024,1)
k_final(const float* __restrict__ pos, const int* __restrict__ efrom, const int* __restrict__ eto,
        const float* __restrict__ tp2, const int* __restrict__ S, const int* __restrict__ numS,
        const float* __restrict__ nmid_g, W3JArg w3, float* __restrict__ out5){
  __shared__ float w3s[675];
  __shared__ float nmid_s[CAP_T*80];
  __shared__ float shs[EB*16];
  __shared__ float tp2s[35];
  __shared__ float acc[5];
  __shared__ int   Te[CAP_T], Tlist[CAP_T], sl_[EB], nTs;
  const int tid=threadIdx.x;
  for(int i=tid;i<675;i+=1024) w3s[i]=w3.w[i];
  if(tid<35) tp2s[tid]=tp2[tid];
  if(tid<5) acc[tid]=0.f;
  int ns=*numS; if(ns>CAP_S) ns=CAP_S;
  int nsc=min(ns,CAP_T);
  if(tid<nsc) Te[tid]=eto[S[tid]];
  __syncthreads();
  if(tid<64){   // identical dedup order as k4 -> identical slots
    bool keep=false; int myv=0;
    if(tid<nsc){
      myv=Te[tid];
      keep=true;
      for(int k=0;k<tid;k++) if(Te[k]==myv){ keep=false; break; }
    }
    unsigned long long mask=__ballot(keep);
    if(keep){
      int slot=__popcll(mask&((1ull<<tid)-1ull));
      Tlist[slot]=myv;
    }
    if(tid==0) nTs=__popcll(mask);
  }
  __syncthreads();
  int nT=nTs;
  for(int i=tid;i<nT*80;i+=1024) nmid_s[i]=nmid_g[i];   // stage once into LDS
  for(int base=0;base<ns;base+=EB){
    int cnt=min(EB,ns-base);
    __syncthreads();
    if(tid<cnt){
      int e=S[base+tid];
      int a=efrom[e], b=eto[e];
      int sl=-1;
      for(int k=0;k<nT;k++) if(Tlist[k]==b){ sl=k; break; }
      sl_[tid]=sl;
      if(sl>=0){
        float dx=pos[3*b]-pos[3*a], dy=pos[3*b+1]-pos[3*a+1], dz=pos[3*b+2]-pos[3*a+2];
        float d=sqrtf(dx*dx+dy*dy+dz*dz);
        float inv=1.f/d;
        calc_sh(dx*inv,dy*inv,dz*inv,&shs[tid*16]);
      }
    }
    __syncthreads();
    for(int t=tid;t<cnt*35;t+=1024){
      int ee=t/35, r=t-ee*35, p=r/5, u=r-p*5;
      int sl=sl_[ee];
      if(sl>=0){
        int l1=(p+1)>>1;                         // 0,1,1,2,2,3,3
        int l2=(0x3636>>(2*p))&3;                // 2,1,3,0,2,1,3
        const unsigned long long wbpack=
          (25ULL<<9)|(70ULL<<18)|(175ULL<<27)|(200ULL<<36)|(325ULL<<45)|(430ULL<<54);
        int wb=(int)((wbpack>>(9*p))&511ULL);    // 0,25,70,175,200,325,430
        int n1=2*l1+1, n2=2*l2+1;
        float tu=tp2s[p*5+u];
        float o0=0.f,o1=0.f,o2=0.f,o3=0.f,o4=0.f;
        const float* mrow=&nmid_s[sl*80+5*l1*l1+u*n1];
        const float* shrow=&shs[ee*16+l2*l2];
        const float* Wp=&w3s[wb];
        for(int i=0;i<n1;i++){
          float mi=mrow[i]*tu;
          for(int j=0;j<n2;j++){
            float c=mi*shrow[j];
            const float* Wk=Wp+(i*n2+j)*5;
            o0+=Wk[0]*c; o1+=Wk[1]*c; o2+=Wk[2]*c; o3+=Wk[3]*c; o4+=Wk[4]*c;
          }
        }
        atomicAdd(&acc[0],o0); atomicAdd(&acc[1],o1); atomicAdd(&acc[2],o2);
        atomicAdd(&acc[3],o3); atomicAdd(&acc[4],o4);
      }
    }
    __syncthreads();
  }
  __syncthreads();
  const float scale=0.37796447300922725f*0.4082482904638631f;  // ALPHA2 * 1/sqrt(6)
  if(tid<5) out5[tid]=acc[tid]*scale;
}

// ====================== launch ======================
extern "C" void kernel_launch(void* const* d_in, const int* in_sizes, int n_in,
                              void* d_out, int out_size, void* d_ws, size_t ws_size,
                              hipStream_t stream){
  const float* x    =(const float*)d_in[0];
  const float* pos  =(const float*)d_in[1];
  const int*   efrom=(const int*)  d_in[2];
  const int*   eto  =(const int*)  d_in[3];
  const float* W1   =(const float*)d_in[4];
  const float* W2   =(const float*)d_in[5];
  const float* tp2  =(const float*)d_in[6];
  int N=in_sizes[0], E=in_sizes[2];
  int HW=(N+3)>>2;

  char* ws=(char*)d_ws;
  size_t o=0;
  unsigned long long* packed=(unsigned long long*)(ws+o); o+=8;
  int* numS=(int*)(ws+o);                   o+=4;
  int* numM=(int*)(ws+o);                   o+=4;
  o=(o+63)&~(size_t)63;
  float* nmid_g=(float*)(ws+o);             o+=(size_t)CAP_T*80*4;
  size_t zlen=o;                            // contiguous zero region: ctrl + nmid (~20.5 KB)
  int* histg=(int*)(ws+o);                  o+=(size_t)NBH*HW*4;   // 800 KB, fully overwritten by k1
  int* S=(int*)(ws+o);                      o+=(size_t)CAP_S*4;
  int* M=(int*)(ws+o);                      o+=(size_t)CAP_M*4;

  (void)hipMemsetAsync(d_ws,0,zlen,stream);

  int nQ=(E+3)>>2;
  int gScan=(nQ+255)/256;
  int gArg =(HW+255)/256;
  k_hist   <<<NBH,1024,0,stream>>>(eto,E,N,histg);
  k_argmax <<<gArg,256,0,stream>>>(histg,N,packed);
  k_collect<<<gScan,256,0,stream>>>(efrom,E,packed,S,numS);
  k_scanM  <<<gScan,256,0,stream>>>(efrom,eto,E,N,S,numS,M,numM);
  k_mlp    <<<16,1024,0,stream>>>(x,pos,efrom,eto,W1,W2,M,numM,nmid_g);
  k_final  <<<1,1024,0,stream>>>(pos,efrom,eto,tp2,S,numS,nmid_g,g_w3j,(float*)d_out);
}